// Round 14
// baseline (133.713 us; speedup 1.0000x reference)
//
#include <hip/hip_runtime.h>
#include <hip/hip_bf16.h>

#define NHEAD 12
#define TSEQ 2048
#define CEMB 768
#define DHEAD 64
#define NBATCH 4

typedef __attribute__((ext_vector_type(8))) short bf16x8;
typedef __attribute__((ext_vector_type(4))) float f32x4;
typedef __attribute__((ext_vector_type(4))) unsigned u32x4;

__device__ __forceinline__ ushort f2bf(float f) {
  union { float f; unsigned u; } v; v.f = f;
  unsigned u = v.u;
  u += 0x7FFFu + ((u >> 16) & 1u);   // RNE to bf16
  return (ushort)(u >> 16);
}

// packed f32x2 -> bf16x2 (1 inst, RNE) — T12 primitive
__device__ __forceinline__ unsigned cvt_pk_bf16(float lo, float hi) {
  unsigned r;
  asm("v_cvt_pk_bf16_f32 %0, %1, %2" : "=v"(r) : "v"(lo), "v"(hi));
  return r;
}

// raw v_exp_f32: D = 2^S0 (scores pre-scaled to log2 domain)
__device__ __forceinline__ float exp2_raw(float x) {
  float r;
  asm("v_exp_f32 %0, %1" : "=v"(r) : "v"(x));
  return r;
}

// v_permlane32_swap_b32: swap a.row1 (lanes 32-63) with b.row0 (lanes 0-31):
// new_a = [a.lanes0-31 | b.lanes0-31], new_b = [a.lanes32-63 | b.lanes32-63]
__device__ __forceinline__ void permswap(unsigned& a, unsigned& b) {
  asm("v_permlane32_swap_b32 %0, %1" : "+v"(a), "+v"(b));
}

// ---------- fused prep: cast x -> bf16, transpose+cast Wa and Wo ----------
__global__ __launch_bounds__(256)
void prep(const float* __restrict__ x, ushort* __restrict__ xb,
          const float* __restrict__ Wa, ushort* __restrict__ WaT,
          const float* __restrict__ Wo, ushort* __restrict__ WoT)
{
  __shared__ float tile[32][33];
  const int bid = blockIdx.x, t = threadIdx.x;
  if (bid < 3072) {
    int i = (bid * 256 + t) * 8;
    float4 v0 = *(const float4*)(x + i);
    float4 v1 = *(const float4*)(x + i + 4);
    bf16x8 wv;
    wv[0] = (short)f2bf(v0.x); wv[1] = (short)f2bf(v0.y);
    wv[2] = (short)f2bf(v0.z); wv[3] = (short)f2bf(v0.w);
    wv[4] = (short)f2bf(v1.x); wv[5] = (short)f2bf(v1.y);
    wv[6] = (short)f2bf(v1.z); wv[7] = (short)f2bf(v1.w);
    *(bf16x8*)(xb + i) = wv;
    return;
  }
  const int b2 = bid - 3072;
  const int bx = b2 % 96, by = b2 / 96;
  const int tx = t & 31, ty = t >> 5;         // (32,8)
  const float* src; ushort* dst; int C, c0;
  if (bx < 72) { src = Wa; dst = WaT; C = 3 * CEMB; c0 = bx * 32; }
  else         { src = Wo; dst = WoT; C = CEMB;     c0 = (bx - 72) * 32; }
  const int r0 = by * 32;
#pragma unroll
  for (int j = 0; j < 4; ++j)
    tile[ty + j * 8][tx] = src[(size_t)(r0 + ty + j * 8) * C + c0 + tx];
  __syncthreads();
#pragma unroll
  for (int j = 0; j < 4; ++j)
    dst[(size_t)(c0 + ty + j * 8) * CEMB + r0 + tx] = f2bf(tile[tx][ty + j * 8]);
}

// ---------- bf16 MFMA GEMM (m97 + 2-phase dbuf): C = A[M][K] * BT[N][K]^T + bias ----------
// EPI=1: q/k scatter to [B,H,T,D] (q pre-scaled by log2e/8); v written DIRECTLY to
// vT [B,H,D,T] (the 4 acc elements are 4 consecutive tokens -> contiguous 8B store).
template<int EPI>
__global__ __launch_bounds__(256)
void gemm_bf16(const ushort* __restrict__ A, const ushort* __restrict__ BT,
               const float* __restrict__ bias, float* __restrict__ outF,
               ushort* __restrict__ qd, ushort* __restrict__ kd, ushort* __restrict__ vd,
               int M, int N, int K)
{
  __shared__ __align__(16) char smem[32768];   // buf p: As @ p*16384, Bs @ +8192
  const int t = threadIdx.x;
  const int lane = t & 63, wv = t >> 6;
  const int cc = lane & 15, gg = lane >> 4;
  const int m0 = blockIdx.y * 128, n0 = blockIdx.x * 128;
  const int wm = (wv >> 1) * 64, wn = (wv & 1) * 64;

  const int o0 = wv * 1024 + lane * 16;
  const int o1 = o0 + 4096;
  const int r0s = o0 >> 6, s0s = (o0 >> 4) & 3;
  const int r1s = o1 >> 6, s1s = (o1 >> 4) & 3;
  const size_t Kb = (size_t)K * 2;
  const char* a0p = (const char*)A  + (size_t)(m0 + r0s) * Kb + ((s0s ^ ((r0s >> 1) & 3)) << 4);
  const char* a1p = (const char*)A  + (size_t)(m0 + r1s) * Kb + ((s1s ^ ((r1s >> 1) & 3)) << 4);
  const char* b0p = (const char*)BT + (size_t)(n0 + r0s) * Kb + ((s0s ^ ((r0s >> 1) & 3)) << 4);
  const char* b1p = (const char*)BT + (size_t)(n0 + r1s) * Kb + ((s1s ^ ((r1s >> 1) & 3)) << 4);

  auto stage_g = [&](int p, int kb) {
    char* As = smem + p * 16384;
    char* Bs = As + 8192;
    __builtin_amdgcn_global_load_lds(
        (const __attribute__((address_space(1))) unsigned*)(a0p + kb),
        (__attribute__((address_space(3))) unsigned*)(As + wv * 1024), 16, 0, 0);
    __builtin_amdgcn_global_load_lds(
        (const __attribute__((address_space(1))) unsigned*)(a1p + kb),
        (__attribute__((address_space(3))) unsigned*)(As + wv * 1024 + 4096), 16, 0, 0);
    __builtin_amdgcn_global_load_lds(
        (const __attribute__((address_space(1))) unsigned*)(b0p + kb),
        (__attribute__((address_space(3))) unsigned*)(Bs + wv * 1024), 16, 0, 0);
    __builtin_amdgcn_global_load_lds(
        (const __attribute__((address_space(1))) unsigned*)(b1p + kb),
        (__attribute__((address_space(3))) unsigned*)(Bs + wv * 1024 + 4096), 16, 0, 0);
  };

  f32x4 acc[4][4];
#pragma unroll
  for (int i = 0; i < 4; ++i)
#pragma unroll
    for (int j = 0; j < 4; ++j) acc[i][j] = (f32x4){0.f, 0.f, 0.f, 0.f};

  const int KB = K * 2;
  stage_g(0, 0);
  asm volatile("s_waitcnt vmcnt(0)" ::: "memory");
  __syncthreads();
  int p = 0;
  for (int kb = 0; kb < KB; kb += 64) {
    if (kb + 64 < KB) stage_g(p ^ 1, kb + 64);   // prefetch next tile (overlaps compute)
    const char* As = smem + p * 16384;
    const char* Bs = As + 8192;
    bf16x8 fa[4], fb[4];
#pragma unroll
    for (int i = 0; i < 4; ++i) {
      const int r = wm + i * 16 + cc;
      fa[i] = *(const bf16x8*)(As + r * 64 + ((gg ^ ((r >> 1) & 3)) << 4));
    }
#pragma unroll
    for (int j = 0; j < 4; ++j) {
      const int r = wn + j * 16 + cc;
      fb[j] = *(const bf16x8*)(Bs + r * 64 + ((gg ^ ((r >> 1) & 3)) << 4));
    }
    __builtin_amdgcn_s_setprio(1);
#pragma unroll
    for (int i = 0; i < 4; ++i)
#pragma unroll
      for (int j = 0; j < 4; ++j)
        acc[i][j] = __builtin_amdgcn_mfma_f32_16x16x32_bf16(fa[i], fb[j], acc[i][j], 0, 0, 0);
    __builtin_amdgcn_s_setprio(0);
    asm volatile("s_waitcnt vmcnt(0)" ::: "memory");   // next tile's stage landed
    __syncthreads();                                   // all waves done reading buf p
    p ^= 1;
  }

#pragma unroll
  for (int i = 0; i < 4; ++i) {
#pragma unroll
    for (int j = 0; j < 4; ++j) {
      int gm0 = m0 + wm + i * 16 + gg * 4;
      int gn  = n0 + wn + j * 16 + cc;
      float bv = bias[gn];
      if (EPI == 0) {
#pragma unroll
        for (int e = 0; e < 4; ++e)
          outF[(size_t)(gm0 + e) * N + gn] = acc[i][j][e] + bv;
      } else {
        int which = gn / CEMB;
        int r = gn - which * CEMB;
        int hh = r >> 6, dd = r & 63;
        int tt0 = gm0 & (TSEQ - 1), bb = gm0 >> 11;   // 4-aligned: same bb for e=0..3
        if (which == 2) {
          // v -> vT [B,H,D,T]: 4 consecutive tokens contiguous, one 8B store
          ushort* dstv = vd + ((size_t)((bb * NHEAD + hh) * DHEAD + dd)) * TSEQ + tt0;
          uint2 pw;
          pw.x = cvt_pk_bf16(acc[i][j][0] + bv, acc[i][j][1] + bv);
          pw.y = cvt_pk_bf16(acc[i][j][2] + bv, acc[i][j][3] + bv);
          *(uint2*)dstv = pw;
        } else {
          ushort* dst = which == 0 ? qd : kd;
          // q scale: 1/sqrt(D) * log2(e) — softmax computed with exp2
          float sc = (which == 0) ? 0.125f * 1.4426950408889634f : 1.0f;
#pragma unroll
          for (int e = 0; e < 4; ++e)
            dst[(size_t)((bb * NHEAD + hh) * TSEQ + tt0 + e) * DHEAD + dd] =
                f2bf((acc[i][j][e] + bv) * sc);
        }
      }
    }
  }
}

// ---------- flash attention (P in registers via permlane32_swap — no P LDS) ----------
// 1-D grid 768; decode maps all 16 bx-blocks of a head onto ONE XCD (T1).
// Block bx handles q-tiles bx and NT-1-bx (balanced, NT+1 key-tiles/wave).
// DS-traffic cut (the R8-R13 plateau was LDS-pipe saturation, ~96KB/block-iter):
// P no longer round-trips LDS. After eager exp, pe pairs are packed with cvt_pk and
// redistributed across the four 16-lane groups by 4x v_permlane32_swap; the resulting
// k-slot permutation (key = kappa with bits 2<->3 swapped) is legal because MFMA sums
// over k — the V A-fragment is read with the SAME map via 2x ds_read_b64 per (dt,kc)
// (same bytes/cycles as the old b128). DS/block-iter 96->80KB; LDS 49152->32768;
// softmax->PV is now register-only (no lgkm fence).
// PV(kt-1) still overlaps softmax(kt); K/V staged dbuf via global_load_lds (rule 21).
// R10 lesson: V stays LDS-staged (direct global vT reads are a 16-line scatter).
__global__ __launch_bounds__(256)
void attn_fwd(const ushort* __restrict__ qg, const ushort* __restrict__ kg,
              const ushort* __restrict__ vTg, ushort* __restrict__ ybb)
{
  // LDS: K[2] @ 0 (2 x 8KB, swizzled), V[2] @ 16384 (2 x 8KB, swizzled)
  __shared__ __align__(16) char smem[32768];
  const int t = threadIdx.x, lane = t & 63, w = t >> 6;
  const int cc = lane & 15, gg = lane >> 4;
  const int NT = TSEQ / 64;
  const int L = blockIdx.x;
  const int r9 = L >> 3;
  const int bx = r9 & 15;
  const int bh = (L & 7) + 8 * (r9 >> 4);     // same bh -> same XCD slot
  const int b = bh / NHEAD, h = bh - b * NHEAD;

  const char* Kg = (const char*)(kg + (size_t)bh * TSEQ * DHEAD);   // [T][64], 128B rows
  const char* Vg = (const char*)(vTg + (size_t)bh * TSEQ * DHEAD);  // [64][T], 4096B rows

  const int srow = lane >> 3;                        // row&7 within 8-row chunk
  const int ssw  = ((lane & 7) * 16) ^ (srow << 4);  // pre-swizzled source colbyte

  bf16x8 ones;
#pragma unroll
  for (int i = 0; i < 8; ++i) ones[i] = (short)0x3F80;   // bf16 1.0

  auto stageK = [&](int pb, int kt) {
#pragma unroll
    for (int i = 0; i < 2; ++i) {
      const int c = w * 2 + i;
      const char* gk = Kg + (size_t)(kt * 64 + c * 8 + srow) * 128 + ssw;
      __builtin_amdgcn_global_load_lds(
          (const __attribute__((address_space(1))) unsigned*)gk,
          (__attribute__((address_space(3))) unsigned*)(smem + pb * 8192 + c * 1024),
          16, 0, 0);
    }
  };
  auto stageV = [&](int pb, int kt) {
#pragma unroll
    for (int i = 0; i < 2; ++i) {
      const int c = w * 2 + i;
      const char* gv = Vg + (size_t)(c * 8 + srow) * (TSEQ * 2) + (size_t)kt * 128 + ssw;
      __builtin_amdgcn_global_load_lds(
          (const __attribute__((address_space(1))) unsigned*)gv,
          (__attribute__((address_space(3))) unsigned*)(smem + 16384 + pb * 8192 + c * 1024),
          16, 0, 0);
    }
  };

  // PV A-operand (V) read with the permuted k-map: for (dt,kc), element j needs
  // key = kc*32 + 16*(gg>>1) + 4*(gg&1) + (j>>2)*8 + (j&3): two 8B pieces.
  auto readV = [&](const char* Vbuf, int rd, int kc) -> bf16x8 {
    const int c1 = kc * 64 + (gg >> 1) * 32;     // 32-aligned chunk base
    const int o8 = (gg & 1) * 8;
    const int sx = (rd & 7) << 4;
    const char* vrow = Vbuf + rd * 128;
    uint2 v0 = *(const uint2*)(vrow + (c1 ^ sx) + o8);
    uint2 v1 = *(const uint2*)(vrow + ((c1 + 16) ^ sx) + o8);
    u32x4 fv = {v0.x, v0.y, v1.x, v1.y};
    return __builtin_bit_cast(bf16x8, fv);
  };

  int p = 0;
  for (int pass = 0; pass < 2; ++pass) {
    const int qt = pass ? (NT - 1 - bx) : bx;
    const int qrow0 = qt * 64 + w * 16;

    const ushort* Qp = qg + ((size_t)bh * TSEQ + qrow0) * DHEAD;
    bf16x8 fq0 = *(const bf16x8*)(Qp + cc * DHEAD + 8 * gg);
    bf16x8 fq1 = *(const bf16x8*)(Qp + cc * DHEAD + 32 + 8 * gg);

    f32x4 o[4];    // O^T: o[dt][e] = O^T[d = dt*16 + gg*4 + e, q = cc]
    f32x4 l4 = (f32x4){0.f, 0.f, 0.f, 0.f};   // MFMA-ones row-sum acc (elems replicated)
#pragma unroll
    for (int i = 0; i < 4; ++i) o[i] = (f32x4){0.f, 0.f, 0.f, 0.f};
    float m = 0.f;            // running max, log2 domain (eager-exp)
    u32x4 pbf[2];             // P fragments (prev tile), permlane-redistributed
    pbf[0] = (u32x4){0, 0, 0, 0}; pbf[1] = (u32x4){0, 0, 0, 0};

    stageK(p, 0);
    asm volatile("s_waitcnt vmcnt(0)" ::: "memory");
    __syncthreads();

    for (int kt = 0; kt <= qt; ++kt) {
      if (kt < qt) stageK(p ^ 1, kt + 1);   // K for next iter
      stageV(p, kt);                        // V consumed next iter (PV(kt))

      // ---- QK(kt) from K[p] ----
      const char* Kl = smem + p * 8192;
      f32x4 st[4];   // st[ct][e] = S^T[key = 16ct + 4gg + e, q = cc]  (log2 domain)
#pragma unroll
      for (int ct = 0; ct < 4; ++ct) st[ct] = (f32x4){0.f, 0.f, 0.f, 0.f};
      __builtin_amdgcn_s_setprio(1);
#pragma unroll
      for (int ct = 0; ct < 4; ++ct) {
        const int r = ct * 16 + cc;
        const char* kb = Kl + r * 128;
        bf16x8 fk0 = *(const bf16x8*)(kb + ((gg * 16) ^ ((r & 7) << 4)));
        bf16x8 fk1 = *(const bf16x8*)(kb + ((64 + gg * 16) ^ ((r & 7) << 4)));
        st[ct] = __builtin_amdgcn_mfma_f32_16x16x32_bf16(fk0, fq0, st[ct], 0, 0, 0);
        st[ct] = __builtin_amdgcn_mfma_f32_16x16x32_bf16(fk1, fq1, st[ct], 0, 0, 0);
      }

      // ---- PV(kt-1) + l-sum(kt-1): P from registers, V from V[p^1] ----
      if (kt > 0) {
        const char* Vprev = smem + 16384 + (p ^ 1) * 8192;
#pragma unroll
        for (int kc = 0; kc < 2; ++kc) {
          bf16x8 pb = __builtin_bit_cast(bf16x8, pbf[kc]);
          l4 = __builtin_amdgcn_mfma_f32_16x16x32_bf16(ones, pb, l4, 0, 0, 0);
#pragma unroll
          for (int dt = 0; dt < 4; ++dt) {
            bf16x8 fv = readV(Vprev, dt * 16 + cc, kc);
            o[dt] = __builtin_amdgcn_mfma_f32_16x16x32_bf16(fv, pb, o[dt], 0, 0, 0);
          }
        }
      }
      __builtin_amdgcn_s_setprio(0);

      // ---- softmax(kt): eager exp with running m ----
      if (kt == qt) {   // causal mask on the diagonal tile
#pragma unroll
        for (int ct = 0; ct < 4; ++ct)
#pragma unroll
          for (int e = 0; e < 4; ++e)
            if (ct * 16 + gg * 4 + e > w * 16 + cc) st[ct][e] = -1e30f;
      }
      f32x4 pe[4];
#pragma unroll
      for (int ct = 0; ct < 4; ++ct)
#pragma unroll
        for (int e = 0; e < 4; ++e) pe[ct][e] = exp2_raw(st[ct][e] - m);
      float ml = fmaxf(fmaxf(st[0][0], st[0][1]), st[0][2]);
      ml = fmaxf(fmaxf(ml, st[0][3]), fmaxf(st[1][0], st[1][1]));
      ml = fmaxf(fmaxf(ml, st[1][2]), fmaxf(st[1][3], st[2][0]));
      ml = fmaxf(fmaxf(ml, st[2][1]), fmaxf(st[2][2], st[2][3]));
      ml = fmaxf(fmaxf(ml, st[3][0]), fmaxf(st[3][1], st[3][2]));
      ml = fmaxf(ml, st[3][3]);
      ml = fmaxf(ml, __shfl_xor(ml, 16, 64));
      ml = fmaxf(ml, __shfl_xor(ml, 32, 64));
      if (!__all(ml - m <= 11.54f)) {   // rare fixup: rescale (no re-exp)
        float mn = fmaxf(m, ml);
        float al = exp2_raw(m - mn);
#pragma unroll
        for (int dt = 0; dt < 4; ++dt)
#pragma unroll
          for (int e = 0; e < 4; ++e) o[dt][e] *= al;
#pragma unroll
        for (int e = 0; e < 4; ++e) l4[e] *= al;
#pragma unroll
        for (int ct = 0; ct < 4; ++ct)
#pragma unroll
          for (int e = 0; e < 4; ++e) pe[ct][e] *= al;
        m = mn;
      }
      // ---- pack + permlane redistribution: P(kt) fragments into registers ----
      {
        unsigned wx0 = cvt_pk_bf16(pe[0][0], pe[0][1]), wy0 = cvt_pk_bf16(pe[0][2], pe[0][3]);
        unsigned wx1 = cvt_pk_bf16(pe[1][0], pe[1][1]), wy1 = cvt_pk_bf16(pe[1][2], pe[1][3]);
        unsigned wx2 = cvt_pk_bf16(pe[2][0], pe[2][1]), wy2 = cvt_pk_bf16(pe[2][2], pe[2][3]);
        unsigned wx3 = cvt_pk_bf16(pe[3][0], pe[3][1]), wy3 = cvt_pk_bf16(pe[3][2], pe[3][3]);
        permswap(wx0, wx1); permswap(wy0, wy1);   // kc=0: ct pair (0,1)
        permswap(wx2, wx3); permswap(wy2, wy3);   // kc=1: ct pair (2,3)
        pbf[0] = (u32x4){wx0, wy0, wx1, wy1};
        pbf[1] = (u32x4){wx2, wy2, wx3, wy3};
      }

      asm volatile("s_waitcnt vmcnt(0)" ::: "memory");   // K(kt+1) + V(kt) landed
      __syncthreads();                                   // all waves done with buf p
      p ^= 1;
    }

    // ---- epilogue: PV(qt) + l-sum(qt) from V[p^1] (post-flip parity) ----
    {
      const char* Vlast = smem + 16384 + (p ^ 1) * 8192;
#pragma unroll
      for (int kc = 0; kc < 2; ++kc) {
        bf16x8 pb = __builtin_bit_cast(bf16x8, pbf[kc]);
        l4 = __builtin_amdgcn_mfma_f32_16x16x32_bf16(ones, pb, l4, 0, 0, 0);
#pragma unroll
        for (int dt = 0; dt < 4; ++dt) {
          bf16x8 fv = readV(Vlast, dt * 16 + cc, kc);
          o[dt] = __builtin_amdgcn_mfma_f32_16x16x32_bf16(fv, pb, o[dt], 0, 0, 0);
        }
      }
    }

    float inv = 1.0f / l4[0];
    ushort* yrow = ybb + (size_t)(b * TSEQ + qrow0 + cc) * CEMB + h * DHEAD;
#pragma unroll
    for (int dt = 0; dt < 4; ++dt) {
      uint2 pw;
      pw.x = cvt_pk_bf16(o[dt][0] * inv, o[dt][1] * inv);
      pw.y = cvt_pk_bf16(o[dt][2] * inv, o[dt][3] * inv);
      *(uint2*)(yrow + dt * 16 + gg * 4) = pw;
    }
  }
}

extern "C" void kernel_launch(void* const* d_in, const int* in_sizes, int n_in,
                              void* d_out, int out_size, void* d_ws, size_t ws_size,
                              hipStream_t stream)
{
  (void)in_sizes; (void)n_in; (void)out_size; (void)ws_size;
  const float* x  = (const float*)d_in[0];
  const float* Wa = (const float*)d_in[1];
  const float* ba = (const float*)d_in[2];
  const float* Wo = (const float*)d_in[3];
  const float* bo = (const float*)d_in[4];
  float* out = (float*)d_out;

  char* p = (char*)d_ws;
  ushort* WaT  = (ushort*)p; p += (size_t)3 * CEMB * CEMB * 2;               // [2304][768] bf16
  ushort* WoT  = (ushort*)p; p += (size_t)CEMB * CEMB * 2;                   // [768][768] bf16
  ushort* xb   = (ushort*)p; p += (size_t)NBATCH * TSEQ * CEMB * 2;          // x bf16 [B*T][C]
  ushort* qb   = (ushort*)p; p += (size_t)NBATCH * NHEAD * TSEQ * DHEAD * 2; // [B,H,T,D]
  ushort* kb   = (ushort*)p; p += (size_t)NBATCH * NHEAD * TSEQ * DHEAD * 2;
  ushort* vT   = (ushort*)p; p += (size_t)NBATCH * NHEAD * TSEQ * DHEAD * 2; // [B,H,D,T] (direct)
  ushort* yb   = (ushort*)p; p += (size_t)NBATCH * TSEQ * CEMB * 2;          // attn out bf16

  prep<<<3072 + 96 * 24, 256, 0, stream>>>(x, xb, Wa, WaT, Wo, WoT);
  gemm_bf16<1><<<dim3(3 * CEMB / 128, NBATCH * TSEQ / 128), 256, 0, stream>>>(
      xb, WaT, ba, nullptr, qb, kb, vT, NBATCH * TSEQ, 3 * CEMB, CEMB);
  attn_fwd<<<dim3(TSEQ / 128 * NBATCH * NHEAD), 256, 0, stream>>>(qb, kb, vT, yb);
  gemm_bf16<0><<<dim3(CEMB / 128, NBATCH * TSEQ / 128), 256, 0, stream>>>(
      yb, WoT, bo, out, nullptr, nullptr, nullptr, NBATCH * TSEQ, CEMB, CEMB);
}

// Round 15
// 129.862 us; speedup vs baseline: 1.0297x; 1.0297x over previous
//
#include <hip/hip_runtime.h>
#include <hip/hip_bf16.h>

#define NHEAD 12
#define TSEQ 2048
#define CEMB 768
#define DHEAD 64
#define NBATCH 4

typedef __attribute__((ext_vector_type(8))) short bf16x8;
typedef __attribute__((ext_vector_type(4))) float f32x4;
typedef __attribute__((ext_vector_type(4))) unsigned u32x4;

__device__ __forceinline__ ushort f2bf(float f) {
  union { float f; unsigned u; } v; v.f = f;
  unsigned u = v.u;
  u += 0x7FFFu + ((u >> 16) & 1u);   // RNE to bf16
  return (ushort)(u >> 16);
}

// packed f32x2 -> bf16x2 (1 inst, RNE) — T12 primitive
__device__ __forceinline__ unsigned cvt_pk_bf16(float lo, float hi) {
  unsigned r;
  asm("v_cvt_pk_bf16_f32 %0, %1, %2" : "=v"(r) : "v"(lo), "v"(hi));
  return r;
}

// raw v_exp_f32: D = 2^S0 (scores pre-scaled to log2 domain)
__device__ __forceinline__ float exp2_raw(float x) {
  float r;
  asm("v_exp_f32 %0, %1" : "=v"(r) : "v"(x));
  return r;
}

// v_permlane32_swap_b32 (semantics VALIDATED by R14 pass):
// new_a = [a.lanes0-31 | b.lanes0-31], new_b = [a.lanes32-63 | b.lanes32-63]
__device__ __forceinline__ void permswap32(unsigned& a, unsigned& b) {
  asm("v_permlane32_swap_b32 %0, %1" : "+v"(a), "+v"(b));
}
// v_permlane16_swap_b32: rows = 16 lanes; swap a's odd rows with b's even rows:
// new_a = [a.r0, b.r0, a.r2, b.r2], new_b = [a.r1, b.r1, a.r3, b.r3]
__device__ __forceinline__ void permswap16(unsigned& a, unsigned& b) {
  asm("v_permlane16_swap_b32 %0, %1" : "+v"(a), "+v"(b));
}

// ---------- fused prep: cast x -> bf16, transpose+cast Wa and Wo ----------
__global__ __launch_bounds__(256)
void prep(const float* __restrict__ x, ushort* __restrict__ xb,
          const float* __restrict__ Wa, ushort* __restrict__ WaT,
          const float* __restrict__ Wo, ushort* __restrict__ WoT)
{
  __shared__ float tile[32][33];
  const int bid = blockIdx.x, t = threadIdx.x;
  if (bid < 3072) {
    int i = (bid * 256 + t) * 8;
    float4 v0 = *(const float4*)(x + i);
    float4 v1 = *(const float4*)(x + i + 4);
    bf16x8 wv;
    wv[0] = (short)f2bf(v0.x); wv[1] = (short)f2bf(v0.y);
    wv[2] = (short)f2bf(v0.z); wv[3] = (short)f2bf(v0.w);
    wv[4] = (short)f2bf(v1.x); wv[5] = (short)f2bf(v1.y);
    wv[6] = (short)f2bf(v1.z); wv[7] = (short)f2bf(v1.w);
    *(bf16x8*)(xb + i) = wv;
    return;
  }
  const int b2 = bid - 3072;
  const int bx = b2 % 96, by = b2 / 96;
  const int tx = t & 31, ty = t >> 5;         // (32,8)
  const float* src; ushort* dst; int C, c0;
  if (bx < 72) { src = Wa; dst = WaT; C = 3 * CEMB; c0 = bx * 32; }
  else         { src = Wo; dst = WoT; C = CEMB;     c0 = (bx - 72) * 32; }
  const int r0 = by * 32;
#pragma unroll
  for (int j = 0; j < 4; ++j)
    tile[ty + j * 8][tx] = src[(size_t)(r0 + ty + j * 8) * C + c0 + tx];
  __syncthreads();
#pragma unroll
  for (int j = 0; j < 4; ++j)
    dst[(size_t)(c0 + ty + j * 8) * CEMB + r0 + tx] = f2bf(tile[tx][ty + j * 8]);
}

// ---------- bf16 MFMA GEMM (m97 + 2-phase dbuf): C = A[M][K] * BT[N][K]^T + bias ----------
// EPI=1: q/k scatter to [B,H,T,D] (q pre-scaled by log2e/8); v written DIRECTLY to
// vT [B,H,D,T] (the 4 acc elements are 4 consecutive tokens -> contiguous 8B store).
template<int EPI>
__global__ __launch_bounds__(256)
void gemm_bf16(const ushort* __restrict__ A, const ushort* __restrict__ BT,
               const float* __restrict__ bias, float* __restrict__ outF,
               ushort* __restrict__ qd, ushort* __restrict__ kd, ushort* __restrict__ vd,
               int M, int N, int K)
{
  __shared__ __align__(16) char smem[32768];   // buf p: As @ p*16384, Bs @ +8192
  const int t = threadIdx.x;
  const int lane = t & 63, wv = t >> 6;
  const int cc = lane & 15, gg = lane >> 4;
  const int m0 = blockIdx.y * 128, n0 = blockIdx.x * 128;
  const int wm = (wv >> 1) * 64, wn = (wv & 1) * 64;

  const int o0 = wv * 1024 + lane * 16;
  const int o1 = o0 + 4096;
  const int r0s = o0 >> 6, s0s = (o0 >> 4) & 3;
  const int r1s = o1 >> 6, s1s = (o1 >> 4) & 3;
  const size_t Kb = (size_t)K * 2;
  const char* a0p = (const char*)A  + (size_t)(m0 + r0s) * Kb + ((s0s ^ ((r0s >> 1) & 3)) << 4);
  const char* a1p = (const char*)A  + (size_t)(m0 + r1s) * Kb + ((s1s ^ ((r1s >> 1) & 3)) << 4);
  const char* b0p = (const char*)BT + (size_t)(n0 + r0s) * Kb + ((s0s ^ ((r0s >> 1) & 3)) << 4);
  const char* b1p = (const char*)BT + (size_t)(n0 + r1s) * Kb + ((s1s ^ ((r1s >> 1) & 3)) << 4);

  auto stage_g = [&](int p, int kb) {
    char* As = smem + p * 16384;
    char* Bs = As + 8192;
    __builtin_amdgcn_global_load_lds(
        (const __attribute__((address_space(1))) unsigned*)(a0p + kb),
        (__attribute__((address_space(3))) unsigned*)(As + wv * 1024), 16, 0, 0);
    __builtin_amdgcn_global_load_lds(
        (const __attribute__((address_space(1))) unsigned*)(a1p + kb),
        (__attribute__((address_space(3))) unsigned*)(As + wv * 1024 + 4096), 16, 0, 0);
    __builtin_amdgcn_global_load_lds(
        (const __attribute__((address_space(1))) unsigned*)(b0p + kb),
        (__attribute__((address_space(3))) unsigned*)(Bs + wv * 1024), 16, 0, 0);
    __builtin_amdgcn_global_load_lds(
        (const __attribute__((address_space(1))) unsigned*)(b1p + kb),
        (__attribute__((address_space(3))) unsigned*)(Bs + wv * 1024 + 4096), 16, 0, 0);
  };

  f32x4 acc[4][4];
#pragma unroll
  for (int i = 0; i < 4; ++i)
#pragma unroll
    for (int j = 0; j < 4; ++j) acc[i][j] = (f32x4){0.f, 0.f, 0.f, 0.f};

  const int KB = K * 2;
  stage_g(0, 0);
  asm volatile("s_waitcnt vmcnt(0)" ::: "memory");
  __syncthreads();
  int p = 0;
  for (int kb = 0; kb < KB; kb += 64) {
    if (kb + 64 < KB) stage_g(p ^ 1, kb + 64);   // prefetch next tile (overlaps compute)
    const char* As = smem + p * 16384;
    const char* Bs = As + 8192;
    bf16x8 fa[4], fb[4];
#pragma unroll
    for (int i = 0; i < 4; ++i) {
      const int r = wm + i * 16 + cc;
      fa[i] = *(const bf16x8*)(As + r * 64 + ((gg ^ ((r >> 1) & 3)) << 4));
    }
#pragma unroll
    for (int j = 0; j < 4; ++j) {
      const int r = wn + j * 16 + cc;
      fb[j] = *(const bf16x8*)(Bs + r * 64 + ((gg ^ ((r >> 1) & 3)) << 4));
    }
    __builtin_amdgcn_s_setprio(1);
#pragma unroll
    for (int i = 0; i < 4; ++i)
#pragma unroll
      for (int j = 0; j < 4; ++j)
        acc[i][j] = __builtin_amdgcn_mfma_f32_16x16x32_bf16(fa[i], fb[j], acc[i][j], 0, 0, 0);
    __builtin_amdgcn_s_setprio(0);
    asm volatile("s_waitcnt vmcnt(0)" ::: "memory");   // next tile's stage landed
    __syncthreads();                                   // all waves done reading buf p
    p ^= 1;
  }

#pragma unroll
  for (int i = 0; i < 4; ++i) {
#pragma unroll
    for (int j = 0; j < 4; ++j) {
      int gm0 = m0 + wm + i * 16 + gg * 4;
      int gn  = n0 + wn + j * 16 + cc;
      float bv = bias[gn];
      if (EPI == 0) {
#pragma unroll
        for (int e = 0; e < 4; ++e)
          outF[(size_t)(gm0 + e) * N + gn] = acc[i][j][e] + bv;
      } else {
        int which = gn / CEMB;
        int r = gn - which * CEMB;
        int hh = r >> 6, dd = r & 63;
        int tt0 = gm0 & (TSEQ - 1), bb = gm0 >> 11;   // 4-aligned: same bb for e=0..3
        if (which == 2) {
          // v -> vT [B,H,D,T]: 4 consecutive tokens contiguous, one 8B store
          ushort* dstv = vd + ((size_t)((bb * NHEAD + hh) * DHEAD + dd)) * TSEQ + tt0;
          uint2 pw;
          pw.x = cvt_pk_bf16(acc[i][j][0] + bv, acc[i][j][1] + bv);
          pw.y = cvt_pk_bf16(acc[i][j][2] + bv, acc[i][j][3] + bv);
          *(uint2*)dstv = pw;
        } else {
          ushort* dst = which == 0 ? qd : kd;
          // q scale: 1/sqrt(D) * log2(e) — softmax computed with exp2
          float sc = (which == 0) ? 0.125f * 1.4426950408889634f : 1.0f;
#pragma unroll
          for (int e = 0; e < 4; ++e)
            dst[(size_t)((bb * NHEAD + hh) * TSEQ + tt0 + e) * DHEAD + dd] =
                f2bf((acc[i][j][e] + bv) * sc);
        }
      }
    }
  }
}

// ---------- flash attention (register-P in STANDARD B-frag layout — no P LDS) ----------
// 1-D grid 768; decode maps all 16 bx-blocks of a head onto ONE XCD (T1).
// Block bx handles q-tiles bx and NT-1-bx (balanced, NT+1 key-tiles/wave).
// R14 lesson: do NOT permute the V read (b64 pattern 4x'd bank conflicts). Instead keep
// V as the proven conflict-free b128 standard-layout fragments and build the STANDARD
// P B-frag in registers: pack S^T pairs with cvt_pk, then per kc
//   chain(X,Y) = permlane16_swap(permlane32_swap(X, Y))
// yields exactly frag words (0,2) from (X0,Y0) and (1,3) from (X1,Y1) — derived from
// B-frag mapping k = 8*(lane>>4) + j, validated-by-absmax like R14's permlane32.
// DS/block-iter 1088 -> 896 cy (P round-trip gone); LDS 32 KB; softmax->PV reg-only.
// Eager-exp softmax (running m, rare rescale fixup), MFMA l-sum, PV(kt-1) overlap.
__global__ __launch_bounds__(256)
void attn_fwd(const ushort* __restrict__ qg, const ushort* __restrict__ kg,
              const ushort* __restrict__ vTg, ushort* __restrict__ ybb)
{
  // LDS: K[2] @ 0 (2 x 8KB, swizzled), V[2] @ 16384 (2 x 8KB, swizzled)
  __shared__ __align__(16) char smem[32768];
  const int t = threadIdx.x, lane = t & 63, w = t >> 6;
  const int cc = lane & 15, gg = lane >> 4;
  const int NT = TSEQ / 64;
  const int L = blockIdx.x;
  const int r9 = L >> 3;
  const int bx = r9 & 15;
  const int bh = (L & 7) + 8 * (r9 >> 4);     // same bh -> same XCD slot
  const int b = bh / NHEAD, h = bh - b * NHEAD;

  const char* Kg = (const char*)(kg + (size_t)bh * TSEQ * DHEAD);   // [T][64], 128B rows
  const char* Vg = (const char*)(vTg + (size_t)bh * TSEQ * DHEAD);  // [64][T], 4096B rows

  const int srow = lane >> 3;                        // row&7 within 8-row chunk
  const int ssw  = ((lane & 7) * 16) ^ (srow << 4);  // pre-swizzled source colbyte

  bf16x8 ones;
#pragma unroll
  for (int i = 0; i < 8; ++i) ones[i] = (short)0x3F80;   // bf16 1.0

  auto stageK = [&](int pb, int kt) {
#pragma unroll
    for (int i = 0; i < 2; ++i) {
      const int c = w * 2 + i;
      const char* gk = Kg + (size_t)(kt * 64 + c * 8 + srow) * 128 + ssw;
      __builtin_amdgcn_global_load_lds(
          (const __attribute__((address_space(1))) unsigned*)gk,
          (__attribute__((address_space(3))) unsigned*)(smem + pb * 8192 + c * 1024),
          16, 0, 0);
    }
  };
  auto stageV = [&](int pb, int kt) {
#pragma unroll
    for (int i = 0; i < 2; ++i) {
      const int c = w * 2 + i;
      const char* gv = Vg + (size_t)(c * 8 + srow) * (TSEQ * 2) + (size_t)kt * 128 + ssw;
      __builtin_amdgcn_global_load_lds(
          (const __attribute__((address_space(1))) unsigned*)gv,
          (__attribute__((address_space(3))) unsigned*)(smem + 16384 + pb * 8192 + c * 1024),
          16, 0, 0);
    }
  };

  int p = 0;
  for (int pass = 0; pass < 2; ++pass) {
    const int qt = pass ? (NT - 1 - bx) : bx;
    const int qrow0 = qt * 64 + w * 16;

    const ushort* Qp = qg + ((size_t)bh * TSEQ + qrow0) * DHEAD;
    bf16x8 fq0 = *(const bf16x8*)(Qp + cc * DHEAD + 8 * gg);
    bf16x8 fq1 = *(const bf16x8*)(Qp + cc * DHEAD + 32 + 8 * gg);

    f32x4 o[4];    // O^T: o[dt][e] = O^T[d = dt*16 + gg*4 + e, q = cc]
    f32x4 l4 = (f32x4){0.f, 0.f, 0.f, 0.f};   // MFMA-ones row-sum acc (elems replicated)
#pragma unroll
    for (int i = 0; i < 4; ++i) o[i] = (f32x4){0.f, 0.f, 0.f, 0.f};
    float m = 0.f;            // running max, log2 domain (eager-exp)
    u32x4 pbf[2];             // P fragments (prev tile), STANDARD B-frag layout
    pbf[0] = (u32x4){0, 0, 0, 0}; pbf[1] = (u32x4){0, 0, 0, 0};

    stageK(p, 0);
    asm volatile("s_waitcnt vmcnt(0)" ::: "memory");
    __syncthreads();

    for (int kt = 0; kt <= qt; ++kt) {
      if (kt < qt) stageK(p ^ 1, kt + 1);   // K for next iter
      stageV(p, kt);                        // V consumed next iter (PV(kt))

      // ---- QK(kt) from K[p] ----
      const char* Kl = smem + p * 8192;
      f32x4 st[4];   // st[ct][e] = S^T[key = 16ct + 4gg + e, q = cc]  (log2 domain)
#pragma unroll
      for (int ct = 0; ct < 4; ++ct) st[ct] = (f32x4){0.f, 0.f, 0.f, 0.f};
      __builtin_amdgcn_s_setprio(1);
#pragma unroll
      for (int ct = 0; ct < 4; ++ct) {
        const int r = ct * 16 + cc;
        const char* kb = Kl + r * 128;
        bf16x8 fk0 = *(const bf16x8*)(kb + ((gg * 16) ^ ((r & 7) << 4)));
        bf16x8 fk1 = *(const bf16x8*)(kb + ((64 + gg * 16) ^ ((r & 7) << 4)));
        st[ct] = __builtin_amdgcn_mfma_f32_16x16x32_bf16(fk0, fq0, st[ct], 0, 0, 0);
        st[ct] = __builtin_amdgcn_mfma_f32_16x16x32_bf16(fk1, fq1, st[ct], 0, 0, 0);
      }

      // ---- PV(kt-1) + l-sum(kt-1): P from registers, V[p^1] standard b128 ----
      if (kt > 0) {
        const char* Vprev = smem + 16384 + (p ^ 1) * 8192;
#pragma unroll
        for (int kc = 0; kc < 2; ++kc) {
          bf16x8 pb = __builtin_bit_cast(bf16x8, pbf[kc]);
          l4 = __builtin_amdgcn_mfma_f32_16x16x32_bf16(ones, pb, l4, 0, 0, 0);
#pragma unroll
          for (int dt = 0; dt < 4; ++dt) {
            const int rd = dt * 16 + cc;
            bf16x8 fv = *(const bf16x8*)(Vprev + rd * 128 + ((kc * 64 + gg * 16) ^ ((rd & 7) << 4)));
            o[dt] = __builtin_amdgcn_mfma_f32_16x16x32_bf16(fv, pb, o[dt], 0, 0, 0);
          }
        }
      }
      __builtin_amdgcn_s_setprio(0);

      // ---- softmax(kt): eager exp with running m ----
      if (kt == qt) {   // causal mask on the diagonal tile
#pragma unroll
        for (int ct = 0; ct < 4; ++ct)
#pragma unroll
          for (int e = 0; e < 4; ++e)
            if (ct * 16 + gg * 4 + e > w * 16 + cc) st[ct][e] = -1e30f;
      }
      f32x4 pe[4];
#pragma unroll
      for (int ct = 0; ct < 4; ++ct)
#pragma unroll
        for (int e = 0; e < 4; ++e) pe[ct][e] = exp2_raw(st[ct][e] - m);
      float ml = fmaxf(fmaxf(st[0][0], st[0][1]), st[0][2]);
      ml = fmaxf(fmaxf(ml, st[0][3]), fmaxf(st[1][0], st[1][1]));
      ml = fmaxf(fmaxf(ml, st[1][2]), fmaxf(st[1][3], st[2][0]));
      ml = fmaxf(fmaxf(ml, st[2][1]), fmaxf(st[2][2], st[2][3]));
      ml = fmaxf(fmaxf(ml, st[3][0]), fmaxf(st[3][1], st[3][2]));
      ml = fmaxf(ml, st[3][3]);
      ml = fmaxf(ml, __shfl_xor(ml, 16, 64));
      ml = fmaxf(ml, __shfl_xor(ml, 32, 64));
      if (!__all(ml - m <= 11.54f)) {   // rare fixup: rescale (no re-exp)
        float mn = fmaxf(m, ml);
        float al = exp2_raw(m - mn);
#pragma unroll
        for (int dt = 0; dt < 4; ++dt)
#pragma unroll
          for (int e = 0; e < 4; ++e) o[dt][e] *= al;
#pragma unroll
        for (int e = 0; e < 4; ++e) l4[e] *= al;
#pragma unroll
        for (int ct = 0; ct < 4; ++ct)
#pragma unroll
          for (int e = 0; e < 4; ++e) pe[ct][e] *= al;
        m = mn;
      }
      // ---- pack + permlane chains: STANDARD B-frag P(kt) into registers ----
      {
        unsigned X0 = cvt_pk_bf16(pe[0][0], pe[0][1]), X1 = cvt_pk_bf16(pe[0][2], pe[0][3]);
        unsigned Y0 = cvt_pk_bf16(pe[1][0], pe[1][1]), Y1 = cvt_pk_bf16(pe[1][2], pe[1][3]);
        unsigned Z0 = cvt_pk_bf16(pe[2][0], pe[2][1]), Z1 = cvt_pk_bf16(pe[2][2], pe[2][3]);
        unsigned W0 = cvt_pk_bf16(pe[3][0], pe[3][1]), W1 = cvt_pk_bf16(pe[3][2], pe[3][3]);
        permswap32(X0, Y0); permswap16(X0, Y0);   // X0 -> words0, Y0 -> words2 (kc=0)
        permswap32(X1, Y1); permswap16(X1, Y1);   // X1 -> words1, Y1 -> words3 (kc=0)
        permswap32(Z0, W0); permswap16(Z0, W0);   // kc=1
        permswap32(Z1, W1); permswap16(Z1, W1);
        pbf[0] = (u32x4){X0, X1, Y0, Y1};
        pbf[1] = (u32x4){Z0, Z1, W0, W1};
      }

      asm volatile("s_waitcnt vmcnt(0)" ::: "memory");   // K(kt+1) + V(kt) landed
      __syncthreads();                                   // all waves done with buf p
      p ^= 1;
    }

    // ---- epilogue: PV(qt) + l-sum(qt) from V[p^1] (post-flip parity) ----
    {
      const char* Vlast = smem + 16384 + (p ^ 1) * 8192;
#pragma unroll
      for (int kc = 0; kc < 2; ++kc) {
        bf16x8 pb = __builtin_bit_cast(bf16x8, pbf[kc]);
        l4 = __builtin_amdgcn_mfma_f32_16x16x32_bf16(ones, pb, l4, 0, 0, 0);
#pragma unroll
        for (int dt = 0; dt < 4; ++dt) {
          const int rd = dt * 16 + cc;
          bf16x8 fv = *(const bf16x8*)(Vlast + rd * 128 + ((kc * 64 + gg * 16) ^ ((rd & 7) << 4)));
          o[dt] = __builtin_amdgcn_mfma_f32_16x16x32_bf16(fv, pb, o[dt], 0, 0, 0);
        }
      }
    }

    float inv = 1.0f / l4[0];
    ushort* yrow = ybb + (size_t)(b * TSEQ + qrow0 + cc) * CEMB + h * DHEAD;
#pragma unroll
    for (int dt = 0; dt < 4; ++dt) {
      uint2 pw;
      pw.x = cvt_pk_bf16(o[dt][0] * inv, o[dt][1] * inv);
      pw.y = cvt_pk_bf16(o[dt][2] * inv, o[dt][3] * inv);
      *(uint2*)(yrow + dt * 16 + gg * 4) = pw;
    }
  }
}

extern "C" void kernel_launch(void* const* d_in, const int* in_sizes, int n_in,
                              void* d_out, int out_size, void* d_ws, size_t ws_size,
                              hipStream_t stream)
{
  (void)in_sizes; (void)n_in; (void)out_size; (void)ws_size;
  const float* x  = (const float*)d_in[0];
  const float* Wa = (const float*)d_in[1];
  const float* ba = (const float*)d_in[2];
  const float* Wo = (const float*)d_in[3];
  const float* bo = (const float*)d_in[4];
  float* out = (float*)d_out;

  char* p = (char*)d_ws;
  ushort* WaT  = (ushort*)p; p += (size_t)3 * CEMB * CEMB * 2;               // [2304][768] bf16
  ushort* WoT  = (ushort*)p; p += (size_t)CEMB * CEMB * 2;                   // [768][768] bf16
  ushort* xb   = (ushort*)p; p += (size_t)NBATCH * TSEQ * CEMB * 2;          // x bf16 [B*T][C]
  ushort* qb   = (ushort*)p; p += (size_t)NBATCH * NHEAD * TSEQ * DHEAD * 2; // [B,H,T,D]
  ushort* kb   = (ushort*)p; p += (size_t)NBATCH * NHEAD * TSEQ * DHEAD * 2;
  ushort* vT   = (ushort*)p; p += (size_t)NBATCH * NHEAD * TSEQ * DHEAD * 2; // [B,H,D,T] (direct)
  ushort* yb   = (ushort*)p; p += (size_t)NBATCH * TSEQ * CEMB * 2;          // attn out bf16

  prep<<<3072 + 96 * 24, 256, 0, stream>>>(x, xb, Wa, WaT, Wo, WoT);
  gemm_bf16<1><<<dim3(3 * CEMB / 128, NBATCH * TSEQ / 128), 256, 0, stream>>>(
      xb, WaT, ba, nullptr, qb, kb, vT, NBATCH * TSEQ, 3 * CEMB, CEMB);
  attn_fwd<<<dim3(TSEQ / 128 * NBATCH * NHEAD), 256, 0, stream>>>(qb, kb, vT, yb);
  gemm_bf16<0><<<dim3(CEMB / 128, NBATCH * TSEQ / 128), 256, 0, stream>>>(
      yb, WoT, bo, out, nullptr, nullptr, nullptr, NBATCH * TSEQ, CEMB, CEMB);
}

// Round 16
// 127.973 us; speedup vs baseline: 1.0448x; 1.0148x over previous
//
#include <hip/hip_runtime.h>
#include <hip/hip_bf16.h>

#define NHEAD 12
#define TSEQ 2048
#define CEMB 768
#define DHEAD 64
#define NBATCH 4

typedef __attribute__((ext_vector_type(8))) short bf16x8;
typedef __attribute__((ext_vector_type(4))) float f32x4;
typedef __attribute__((ext_vector_type(4))) unsigned u32x4;

__device__ __forceinline__ ushort f2bf(float f) {
  union { float f; unsigned u; } v; v.f = f;
  unsigned u = v.u;
  u += 0x7FFFu + ((u >> 16) & 1u);   // RNE to bf16
  return (ushort)(u >> 16);
}

// packed f32x2 -> bf16x2 (1 inst, RNE) — T12 primitive
__device__ __forceinline__ unsigned cvt_pk_bf16(float lo, float hi) {
  unsigned r;
  asm("v_cvt_pk_bf16_f32 %0, %1, %2" : "=v"(r) : "v"(lo), "v"(hi));
  return r;
}

// raw v_exp_f32: D = 2^S0 (scores pre-scaled to log2 domain)
__device__ __forceinline__ float exp2_raw(float x) {
  float r;
  asm("v_exp_f32 %0, %1" : "=v"(r) : "v"(x));
  return r;
}

// v_permlane32_swap_b32 (semantics validated R14):
// new_a = [a.lanes0-31 | b.lanes0-31], new_b = [a.lanes32-63 | b.lanes32-63]
__device__ __forceinline__ void permswap32(unsigned& a, unsigned& b) {
  asm("v_permlane32_swap_b32 %0, %1" : "+v"(a), "+v"(b));
}
// v_permlane16_swap_b32 (validated R15): swap a's odd 16-rows with b's even 16-rows
__device__ __forceinline__ void permswap16(unsigned& a, unsigned& b) {
  asm("v_permlane16_swap_b32 %0, %1" : "+v"(a), "+v"(b));
}

// ---------- fused prep: cast x -> bf16, transpose+cast Wa and Wo ----------
__global__ __launch_bounds__(256)
void prep(const float* __restrict__ x, ushort* __restrict__ xb,
          const float* __restrict__ Wa, ushort* __restrict__ WaT,
          const float* __restrict__ Wo, ushort* __restrict__ WoT)
{
  __shared__ float tile[32][33];
  const int bid = blockIdx.x, t = threadIdx.x;
  if (bid < 3072) {
    int i = (bid * 256 + t) * 8;
    float4 v0 = *(const float4*)(x + i);
    float4 v1 = *(const float4*)(x + i + 4);
    bf16x8 wv;
    wv[0] = (short)f2bf(v0.x); wv[1] = (short)f2bf(v0.y);
    wv[2] = (short)f2bf(v0.z); wv[3] = (short)f2bf(v0.w);
    wv[4] = (short)f2bf(v1.x); wv[5] = (short)f2bf(v1.y);
    wv[6] = (short)f2bf(v1.z); wv[7] = (short)f2bf(v1.w);
    *(bf16x8*)(xb + i) = wv;
    return;
  }
  const int b2 = bid - 3072;
  const int bx = b2 % 96, by = b2 / 96;
  const int tx = t & 31, ty = t >> 5;         // (32,8)
  const float* src; ushort* dst; int C, c0;
  if (bx < 72) { src = Wa; dst = WaT; C = 3 * CEMB; c0 = bx * 32; }
  else         { src = Wo; dst = WoT; C = CEMB;     c0 = (bx - 72) * 32; }
  const int r0 = by * 32;
#pragma unroll
  for (int j = 0; j < 4; ++j)
    tile[ty + j * 8][tx] = src[(size_t)(r0 + ty + j * 8) * C + c0 + tx];
  __syncthreads();
#pragma unroll
  for (int j = 0; j < 4; ++j)
    dst[(size_t)(c0 + ty + j * 8) * CEMB + r0 + tx] = f2bf(tile[tx][ty + j * 8]);
}

// ---------- bf16 MFMA GEMM (m97 + 2-phase dbuf): C = A[M][K] * BT[N][K]^T + bias ----------
// EPI=1: q/k scatter to [B,H,T,D] (q pre-scaled by log2e/8); v written DIRECTLY to
// vT [B,H,D,T] (the 4 acc elements are 4 consecutive tokens -> contiguous 8B store).
template<int EPI>
__global__ __launch_bounds__(256)
void gemm_bf16(const ushort* __restrict__ A, const ushort* __restrict__ BT,
               const float* __restrict__ bias, float* __restrict__ outF,
               ushort* __restrict__ qd, ushort* __restrict__ kd, ushort* __restrict__ vd,
               int M, int N, int K)
{
  __shared__ __align__(16) char smem[32768];   // buf p: As @ p*16384, Bs @ +8192
  const int t = threadIdx.x;
  const int lane = t & 63, wv = t >> 6;
  const int cc = lane & 15, gg = lane >> 4;
  const int m0 = blockIdx.y * 128, n0 = blockIdx.x * 128;
  const int wm = (wv >> 1) * 64, wn = (wv & 1) * 64;

  const int o0 = wv * 1024 + lane * 16;
  const int o1 = o0 + 4096;
  const int r0s = o0 >> 6, s0s = (o0 >> 4) & 3;
  const int r1s = o1 >> 6, s1s = (o1 >> 4) & 3;
  const size_t Kb = (size_t)K * 2;
  const char* a0p = (const char*)A  + (size_t)(m0 + r0s) * Kb + ((s0s ^ ((r0s >> 1) & 3)) << 4);
  const char* a1p = (const char*)A  + (size_t)(m0 + r1s) * Kb + ((s1s ^ ((r1s >> 1) & 3)) << 4);
  const char* b0p = (const char*)BT + (size_t)(n0 + r0s) * Kb + ((s0s ^ ((r0s >> 1) & 3)) << 4);
  const char* b1p = (const char*)BT + (size_t)(n0 + r1s) * Kb + ((s1s ^ ((r1s >> 1) & 3)) << 4);

  auto stage_g = [&](int p, int kb) {
    char* As = smem + p * 16384;
    char* Bs = As + 8192;
    __builtin_amdgcn_global_load_lds(
        (const __attribute__((address_space(1))) unsigned*)(a0p + kb),
        (__attribute__((address_space(3))) unsigned*)(As + wv * 1024), 16, 0, 0);
    __builtin_amdgcn_global_load_lds(
        (const __attribute__((address_space(1))) unsigned*)(a1p + kb),
        (__attribute__((address_space(3))) unsigned*)(As + wv * 1024 + 4096), 16, 0, 0);
    __builtin_amdgcn_global_load_lds(
        (const __attribute__((address_space(1))) unsigned*)(b0p + kb),
        (__attribute__((address_space(3))) unsigned*)(Bs + wv * 1024), 16, 0, 0);
    __builtin_amdgcn_global_load_lds(
        (const __attribute__((address_space(1))) unsigned*)(b1p + kb),
        (__attribute__((address_space(3))) unsigned*)(Bs + wv * 1024 + 4096), 16, 0, 0);
  };

  f32x4 acc[4][4];
#pragma unroll
  for (int i = 0; i < 4; ++i)
#pragma unroll
    for (int j = 0; j < 4; ++j) acc[i][j] = (f32x4){0.f, 0.f, 0.f, 0.f};

  const int KB = K * 2;
  stage_g(0, 0);
  asm volatile("s_waitcnt vmcnt(0)" ::: "memory");
  __syncthreads();
  int p = 0;
  for (int kb = 0; kb < KB; kb += 64) {
    if (kb + 64 < KB) stage_g(p ^ 1, kb + 64);   // prefetch next tile (overlaps compute)
    const char* As = smem + p * 16384;
    const char* Bs = As + 8192;
    bf16x8 fa[4], fb[4];
#pragma unroll
    for (int i = 0; i < 4; ++i) {
      const int r = wm + i * 16 + cc;
      fa[i] = *(const bf16x8*)(As + r * 64 + ((gg ^ ((r >> 1) & 3)) << 4));
    }
#pragma unroll
    for (int j = 0; j < 4; ++j) {
      const int r = wn + j * 16 + cc;
      fb[j] = *(const bf16x8*)(Bs + r * 64 + ((gg ^ ((r >> 1) & 3)) << 4));
    }
    __builtin_amdgcn_s_setprio(1);
#pragma unroll
    for (int i = 0; i < 4; ++i)
#pragma unroll
      for (int j = 0; j < 4; ++j)
        acc[i][j] = __builtin_amdgcn_mfma_f32_16x16x32_bf16(fa[i], fb[j], acc[i][j], 0, 0, 0);
    __builtin_amdgcn_s_setprio(0);
    asm volatile("s_waitcnt vmcnt(0)" ::: "memory");   // next tile's stage landed
    __syncthreads();                                   // all waves done reading buf p
    p ^= 1;
  }

#pragma unroll
  for (int i = 0; i < 4; ++i) {
#pragma unroll
    for (int j = 0; j < 4; ++j) {
      int gm0 = m0 + wm + i * 16 + gg * 4;
      int gn  = n0 + wn + j * 16 + cc;
      float bv = bias[gn];
      if (EPI == 0) {
#pragma unroll
        for (int e = 0; e < 4; ++e)
          outF[(size_t)(gm0 + e) * N + gn] = acc[i][j][e] + bv;
      } else {
        int which = gn / CEMB;
        int r = gn - which * CEMB;
        int hh = r >> 6, dd = r & 63;
        int tt0 = gm0 & (TSEQ - 1), bb = gm0 >> 11;   // 4-aligned: same bb for e=0..3
        if (which == 2) {
          // v -> vT [B,H,D,T]: 4 consecutive tokens contiguous, one 8B store
          ushort* dstv = vd + ((size_t)((bb * NHEAD + hh) * DHEAD + dd)) * TSEQ + tt0;
          uint2 pw;
          pw.x = cvt_pk_bf16(acc[i][j][0] + bv, acc[i][j][1] + bv);
          pw.y = cvt_pk_bf16(acc[i][j][2] + bv, acc[i][j][3] + bv);
          *(uint2*)dstv = pw;
        } else {
          ushort* dst = which == 0 ? qd : kd;
          // q scale: 1/sqrt(D) * log2(e) — softmax computed with exp2
          float sc = (which == 0) ? 0.125f * 1.4426950408889634f : 1.0f;
#pragma unroll
          for (int e = 0; e < 4; ++e)
            dst[(size_t)((bb * NHEAD + hh) * TSEQ + tt0 + e) * DHEAD + dd] =
                f2bf((acc[i][j][e] + bv) * sc);
        }
      }
    }
  }
}

// ---------- flash attention (oversubscribed heavy-first grid, register-P) ----------
// R15 was latency-bound at 12 waves/CU (no pipe >70%) with a grid-capped wave count.
// Now: 1536 blocks (one 64-row q-tile each, 6144 waves). LDS 32KB -> residency 5
// blocks/CU (1280 < 1536) so the dispatch queue BACKFILLS (unlike R3's all-resident
// convoy). Global heavy-first (LPT) order: qt = 31 - (L>>3)/6 — all 32-iter blocks
// dispatch first, 1-iter blocks fill the tail. slot = L&7 keeps same-head -> same-XCD.
// Per-block structure identical to R15: K/V dbuf via global_load_lds (rule 21 swizzle),
// register-P (cvt_pk + permlane32/16 chains -> standard B-frag), eager-exp softmax,
// MFMA l-sum, PV(kt-1) overlapping softmax(kt).
__global__ __launch_bounds__(256)
void attn_fwd(const ushort* __restrict__ qg, const ushort* __restrict__ kg,
              const ushort* __restrict__ vTg, ushort* __restrict__ ybb)
{
  // LDS: K[2] @ 0 (2 x 8KB, swizzled), V[2] @ 16384 (2 x 8KB, swizzled)
  __shared__ __align__(16) char smem[32768];
  const int t = threadIdx.x, lane = t & 63, w = t >> 6;
  const int cc = lane & 15, gg = lane >> 4;
  const int L = blockIdx.x;
  const int slot = L & 7, j = L >> 3;          // j in [0,192)
  const int qt = 31 - j / 6;                   // heavy-first (LPT)
  const int bh = slot + 8 * (j % 6);           // same bh -> same XCD slot
  const int b = bh / NHEAD, h = bh - b * NHEAD;

  const char* Kg = (const char*)(kg + (size_t)bh * TSEQ * DHEAD);   // [T][64], 128B rows
  const char* Vg = (const char*)(vTg + (size_t)bh * TSEQ * DHEAD);  // [64][T], 4096B rows

  const int srow = lane >> 3;                        // row&7 within 8-row chunk
  const int ssw  = ((lane & 7) * 16) ^ (srow << 4);  // pre-swizzled source colbyte

  bf16x8 ones;
#pragma unroll
  for (int i = 0; i < 8; ++i) ones[i] = (short)0x3F80;   // bf16 1.0

  auto stageK = [&](int pb, int kt) {
#pragma unroll
    for (int i = 0; i < 2; ++i) {
      const int c = w * 2 + i;
      const char* gk = Kg + (size_t)(kt * 64 + c * 8 + srow) * 128 + ssw;
      __builtin_amdgcn_global_load_lds(
          (const __attribute__((address_space(1))) unsigned*)gk,
          (__attribute__((address_space(3))) unsigned*)(smem + pb * 8192 + c * 1024),
          16, 0, 0);
    }
  };
  auto stageV = [&](int pb, int kt) {
#pragma unroll
    for (int i = 0; i < 2; ++i) {
      const int c = w * 2 + i;
      const char* gv = Vg + (size_t)(c * 8 + srow) * (TSEQ * 2) + (size_t)kt * 128 + ssw;
      __builtin_amdgcn_global_load_lds(
          (const __attribute__((address_space(1))) unsigned*)gv,
          (__attribute__((address_space(3))) unsigned*)(smem + 16384 + pb * 8192 + c * 1024),
          16, 0, 0);
    }
  };

  const int qrow0 = qt * 64 + w * 16;

  const ushort* Qp = qg + ((size_t)bh * TSEQ + qrow0) * DHEAD;
  bf16x8 fq0 = *(const bf16x8*)(Qp + cc * DHEAD + 8 * gg);
  bf16x8 fq1 = *(const bf16x8*)(Qp + cc * DHEAD + 32 + 8 * gg);

  f32x4 o[4];    // O^T: o[dt][e] = O^T[d = dt*16 + gg*4 + e, q = cc]
  f32x4 l4 = (f32x4){0.f, 0.f, 0.f, 0.f};   // MFMA-ones row-sum acc (elems replicated)
#pragma unroll
  for (int i = 0; i < 4; ++i) o[i] = (f32x4){0.f, 0.f, 0.f, 0.f};
  float m = 0.f;            // running max, log2 domain (eager-exp)
  u32x4 pbf[2];             // P fragments (prev tile), STANDARD B-frag layout
  pbf[0] = (u32x4){0, 0, 0, 0}; pbf[1] = (u32x4){0, 0, 0, 0};

  int p = 0;
  stageK(p, 0);
  asm volatile("s_waitcnt vmcnt(0)" ::: "memory");
  __syncthreads();

  for (int kt = 0; kt <= qt; ++kt) {
    if (kt < qt) stageK(p ^ 1, kt + 1);   // K for next iter
    stageV(p, kt);                        // V consumed next iter (PV(kt))

    // ---- QK(kt) from K[p] ----
    const char* Kl = smem + p * 8192;
    f32x4 st[4];   // st[ct][e] = S^T[key = 16ct + 4gg + e, q = cc]  (log2 domain)
#pragma unroll
    for (int ct = 0; ct < 4; ++ct) st[ct] = (f32x4){0.f, 0.f, 0.f, 0.f};
    __builtin_amdgcn_s_setprio(1);
#pragma unroll
    for (int ct = 0; ct < 4; ++ct) {
      const int r = ct * 16 + cc;
      const char* kb = Kl + r * 128;
      bf16x8 fk0 = *(const bf16x8*)(kb + ((gg * 16) ^ ((r & 7) << 4)));
      bf16x8 fk1 = *(const bf16x8*)(kb + ((64 + gg * 16) ^ ((r & 7) << 4)));
      st[ct] = __builtin_amdgcn_mfma_f32_16x16x32_bf16(fk0, fq0, st[ct], 0, 0, 0);
      st[ct] = __builtin_amdgcn_mfma_f32_16x16x32_bf16(fk1, fq1, st[ct], 0, 0, 0);
    }

    // ---- PV(kt-1) + l-sum(kt-1): P from registers, V[p^1] standard b128 ----
    if (kt > 0) {
      const char* Vprev = smem + 16384 + (p ^ 1) * 8192;
#pragma unroll
      for (int kc = 0; kc < 2; ++kc) {
        bf16x8 pb = __builtin_bit_cast(bf16x8, pbf[kc]);
        l4 = __builtin_amdgcn_mfma_f32_16x16x32_bf16(ones, pb, l4, 0, 0, 0);
#pragma unroll
        for (int dt = 0; dt < 4; ++dt) {
          const int rd = dt * 16 + cc;
          bf16x8 fv = *(const bf16x8*)(Vprev + rd * 128 + ((kc * 64 + gg * 16) ^ ((rd & 7) << 4)));
          o[dt] = __builtin_amdgcn_mfma_f32_16x16x32_bf16(fv, pb, o[dt], 0, 0, 0);
        }
      }
    }
    __builtin_amdgcn_s_setprio(0);

    // ---- softmax(kt): eager exp with running m ----
    if (kt == qt) {   // causal mask on the diagonal tile
#pragma unroll
      for (int ct = 0; ct < 4; ++ct)
#pragma unroll
        for (int e = 0; e < 4; ++e)
          if (ct * 16 + gg * 4 + e > w * 16 + cc) st[ct][e] = -1e30f;
    }
    f32x4 pe[4];
#pragma unroll
    for (int ct = 0; ct < 4; ++ct)
#pragma unroll
      for (int e = 0; e < 4; ++e) pe[ct][e] = exp2_raw(st[ct][e] - m);
    float ml = fmaxf(fmaxf(st[0][0], st[0][1]), st[0][2]);
    ml = fmaxf(fmaxf(ml, st[0][3]), fmaxf(st[1][0], st[1][1]));
    ml = fmaxf(fmaxf(ml, st[1][2]), fmaxf(st[1][3], st[2][0]));
    ml = fmaxf(fmaxf(ml, st[2][1]), fmaxf(st[2][2], st[2][3]));
    ml = fmaxf(fmaxf(ml, st[3][0]), fmaxf(st[3][1], st[3][2]));
    ml = fmaxf(ml, st[3][3]);
    ml = fmaxf(ml, __shfl_xor(ml, 16, 64));
    ml = fmaxf(ml, __shfl_xor(ml, 32, 64));
    if (!__all(ml - m <= 11.54f)) {   // rare fixup: rescale (no re-exp)
      float mn = fmaxf(m, ml);
      float al = exp2_raw(m - mn);
#pragma unroll
      for (int dt = 0; dt < 4; ++dt)
#pragma unroll
        for (int e = 0; e < 4; ++e) o[dt][e] *= al;
#pragma unroll
      for (int e = 0; e < 4; ++e) l4[e] *= al;
#pragma unroll
      for (int ct = 0; ct < 4; ++ct)
#pragma unroll
        for (int e = 0; e < 4; ++e) pe[ct][e] *= al;
      m = mn;
    }
    // ---- pack + permlane chains: STANDARD B-frag P(kt) into registers ----
    {
      unsigned X0 = cvt_pk_bf16(pe[0][0], pe[0][1]), X1 = cvt_pk_bf16(pe[0][2], pe[0][3]);
      unsigned Y0 = cvt_pk_bf16(pe[1][0], pe[1][1]), Y1 = cvt_pk_bf16(pe[1][2], pe[1][3]);
      unsigned Z0 = cvt_pk_bf16(pe[2][0], pe[2][1]), Z1 = cvt_pk_bf16(pe[2][2], pe[2][3]);
      unsigned W0 = cvt_pk_bf16(pe[3][0], pe[3][1]), W1 = cvt_pk_bf16(pe[3][2], pe[3][3]);
      permswap32(X0, Y0); permswap16(X0, Y0);   // X0 -> words0, Y0 -> words2 (kc=0)
      permswap32(X1, Y1); permswap16(X1, Y1);   // X1 -> words1, Y1 -> words3 (kc=0)
      permswap32(Z0, W0); permswap16(Z0, W0);   // kc=1
      permswap32(Z1, W1); permswap16(Z1, W1);
      pbf[0] = (u32x4){X0, X1, Y0, Y1};
      pbf[1] = (u32x4){Z0, Z1, W0, W1};
    }

    asm volatile("s_waitcnt vmcnt(0)" ::: "memory");   // K(kt+1) + V(kt) landed
    __syncthreads();                                   // all waves done with buf p
    p ^= 1;
  }

  // ---- epilogue: PV(qt) + l-sum(qt) from V[p^1] (post-flip parity) ----
  {
    const char* Vlast = smem + 16384 + (p ^ 1) * 8192;
#pragma unroll
    for (int kc = 0; kc < 2; ++kc) {
      bf16x8 pb = __builtin_bit_cast(bf16x8, pbf[kc]);
      l4 = __builtin_amdgcn_mfma_f32_16x16x32_bf16(ones, pb, l4, 0, 0, 0);
#pragma unroll
      for (int dt = 0; dt < 4; ++dt) {
        const int rd = dt * 16 + cc;
        bf16x8 fv = *(const bf16x8*)(Vlast + rd * 128 + ((kc * 64 + gg * 16) ^ ((rd & 7) << 4)));
        o[dt] = __builtin_amdgcn_mfma_f32_16x16x32_bf16(fv, pb, o[dt], 0, 0, 0);
      }
    }
  }

  float inv = 1.0f / l4[0];
  ushort* yrow = ybb + (size_t)(b * TSEQ + qrow0 + cc) * CEMB + h * DHEAD;
#pragma unroll
  for (int dt = 0; dt < 4; ++dt) {
    uint2 pw;
    pw.x = cvt_pk_bf16(o[dt][0] * inv, o[dt][1] * inv);
    pw.y = cvt_pk_bf16(o[dt][2] * inv, o[dt][3] * inv);
    *(uint2*)(yrow + dt * 16 + gg * 4) = pw;
  }
}

extern "C" void kernel_launch(void* const* d_in, const int* in_sizes, int n_in,
                              void* d_out, int out_size, void* d_ws, size_t ws_size,
                              hipStream_t stream)
{
  (void)in_sizes; (void)n_in; (void)out_size; (void)ws_size;
  const float* x  = (const float*)d_in[0];
  const float* Wa = (const float*)d_in[1];
  const float* ba = (const float*)d_in[2];
  const float* Wo = (const float*)d_in[3];
  const float* bo = (const float*)d_in[4];
  float* out = (float*)d_out;

  char* p = (char*)d_ws;
  ushort* WaT  = (ushort*)p; p += (size_t)3 * CEMB * CEMB * 2;               // [2304][768] bf16
  ushort* WoT  = (ushort*)p; p += (size_t)CEMB * CEMB * 2;                   // [768][768] bf16
  ushort* xb   = (ushort*)p; p += (size_t)NBATCH * TSEQ * CEMB * 2;          // x bf16 [B*T][C]
  ushort* qb   = (ushort*)p; p += (size_t)NBATCH * NHEAD * TSEQ * DHEAD * 2; // [B,H,T,D]
  ushort* kb   = (ushort*)p; p += (size_t)NBATCH * NHEAD * TSEQ * DHEAD * 2;
  ushort* vT   = (ushort*)p; p += (size_t)NBATCH * NHEAD * TSEQ * DHEAD * 2; // [B,H,D,T] (direct)
  ushort* yb   = (ushort*)p; p += (size_t)NBATCH * TSEQ * CEMB * 2;          // attn out bf16

  prep<<<3072 + 96 * 24, 256, 0, stream>>>(x, xb, Wa, WaT, Wo, WoT);
  gemm_bf16<1><<<dim3(3 * CEMB / 128, NBATCH * TSEQ / 128), 256, 0, stream>>>(
      xb, WaT, ba, nullptr, qb, kb, vT, NBATCH * TSEQ, 3 * CEMB, CEMB);
  attn_fwd<<<dim3(1536), 256, 0, stream>>>(qb, kb, vT, yb);
  gemm_bf16<0><<<dim3(CEMB / 128, NBATCH * TSEQ / 128), 256, 0, stream>>>(
      yb, WoT, bo, out, nullptr, nullptr, nullptr, NBATCH * TSEQ, CEMB, CEMB);
}

// Round 17
// 118.866 us; speedup vs baseline: 1.1249x; 1.0766x over previous
//
#include <hip/hip_runtime.h>
#include <hip/hip_bf16.h>

#define NHEAD 12
#define TSEQ 2048
#define CEMB 768
#define DHEAD 64
#define NBATCH 4

typedef __attribute__((ext_vector_type(8))) short bf16x8;
typedef __attribute__((ext_vector_type(4))) float f32x4;
typedef __attribute__((ext_vector_type(4))) unsigned u32x4;

template <int N> struct IC { static constexpr int value = N; };

__device__ __forceinline__ ushort f2bf(float f) {
  union { float f; unsigned u; } v; v.f = f;
  unsigned u = v.u;
  u += 0x7FFFu + ((u >> 16) & 1u);   // RNE to bf16
  return (ushort)(u >> 16);
}

// packed f32x2 -> bf16x2 (1 inst, RNE) — T12 primitive
__device__ __forceinline__ unsigned cvt_pk_bf16(float lo, float hi) {
  unsigned r;
  asm("v_cvt_pk_bf16_f32 %0, %1, %2" : "=v"(r) : "v"(lo), "v"(hi));
  return r;
}

// raw v_exp_f32: D = 2^S0 (scores pre-scaled to log2 domain)
__device__ __forceinline__ float exp2_raw(float x) {
  float r;
  asm("v_exp_f32 %0, %1" : "=v"(r) : "v"(x));
  return r;
}

// v_permlane32_swap_b32 (semantics validated R14):
// new_a = [a.lanes0-31 | b.lanes0-31], new_b = [a.lanes32-63 | b.lanes32-63]
__device__ __forceinline__ void permswap32(unsigned& a, unsigned& b) {
  asm("v_permlane32_swap_b32 %0, %1" : "+v"(a), "+v"(b));
}
// v_permlane16_swap_b32 (validated R15): swap a's odd 16-rows with b's even 16-rows
__device__ __forceinline__ void permswap16(unsigned& a, unsigned& b) {
  asm("v_permlane16_swap_b32 %0, %1" : "+v"(a), "+v"(b));
}

// ---------- fused prep: cast x -> bf16, transpose+cast Wa and Wo ----------
__global__ __launch_bounds__(256)
void prep(const float* __restrict__ x, ushort* __restrict__ xb,
          const float* __restrict__ Wa, ushort* __restrict__ WaT,
          const float* __restrict__ Wo, ushort* __restrict__ WoT)
{
  __shared__ float tile[32][33];
  const int bid = blockIdx.x, t = threadIdx.x;
  if (bid < 3072) {
    int i = (bid * 256 + t) * 8;
    float4 v0 = *(const float4*)(x + i);
    float4 v1 = *(const float4*)(x + i + 4);
    bf16x8 wv;
    wv[0] = (short)f2bf(v0.x); wv[1] = (short)f2bf(v0.y);
    wv[2] = (short)f2bf(v0.z); wv[3] = (short)f2bf(v0.w);
    wv[4] = (short)f2bf(v1.x); wv[5] = (short)f2bf(v1.y);
    wv[6] = (short)f2bf(v1.z); wv[7] = (short)f2bf(v1.w);
    *(bf16x8*)(xb + i) = wv;
    return;
  }
  const int b2 = bid - 3072;
  const int bx = b2 % 96, by = b2 / 96;
  const int tx = t & 31, ty = t >> 5;         // (32,8)
  const float* src; ushort* dst; int C, c0;
  if (bx < 72) { src = Wa; dst = WaT; C = 3 * CEMB; c0 = bx * 32; }
  else         { src = Wo; dst = WoT; C = CEMB;     c0 = (bx - 72) * 32; }
  const int r0 = by * 32;
#pragma unroll
  for (int j = 0; j < 4; ++j)
    tile[ty + j * 8][tx] = src[(size_t)(r0 + ty + j * 8) * C + c0 + tx];
  __syncthreads();
#pragma unroll
  for (int j = 0; j < 4; ++j)
    dst[(size_t)(c0 + ty + j * 8) * CEMB + r0 + tx] = f2bf(tile[tx][ty + j * 8]);
}

// ---------- bf16 MFMA GEMM (m97 + 2-phase dbuf): C = A[M][K] * BT[N][K]^T + bias ----------
// EPI=1: q/k scatter to [B,H,T,D] (q pre-scaled by log2e/8); v written DIRECTLY to
// vT [B,H,D,T] (the 4 acc elements are 4 consecutive tokens -> contiguous 8B store).
template<int EPI>
__global__ __launch_bounds__(256)
void gemm_bf16(const ushort* __restrict__ A, const ushort* __restrict__ BT,
               const float* __restrict__ bias, float* __restrict__ outF,
               ushort* __restrict__ qd, ushort* __restrict__ kd, ushort* __restrict__ vd,
               int M, int N, int K)
{
  __shared__ __align__(16) char smem[32768];   // buf p: As @ p*16384, Bs @ +8192
  const int t = threadIdx.x;
  const int lane = t & 63, wv = t >> 6;
  const int cc = lane & 15, gg = lane >> 4;
  const int m0 = blockIdx.y * 128, n0 = blockIdx.x * 128;
  const int wm = (wv >> 1) * 64, wn = (wv & 1) * 64;

  const int o0 = wv * 1024 + lane * 16;
  const int o1 = o0 + 4096;
  const int r0s = o0 >> 6, s0s = (o0 >> 4) & 3;
  const int r1s = o1 >> 6, s1s = (o1 >> 4) & 3;
  const size_t Kb = (size_t)K * 2;
  const char* a0p = (const char*)A  + (size_t)(m0 + r0s) * Kb + ((s0s ^ ((r0s >> 1) & 3)) << 4);
  const char* a1p = (const char*)A  + (size_t)(m0 + r1s) * Kb + ((s1s ^ ((r1s >> 1) & 3)) << 4);
  const char* b0p = (const char*)BT + (size_t)(n0 + r0s) * Kb + ((s0s ^ ((r0s >> 1) & 3)) << 4);
  const char* b1p = (const char*)BT + (size_t)(n0 + r1s) * Kb + ((s1s ^ ((r1s >> 1) & 3)) << 4);

  auto stage_g = [&](int p, int kb) {
    char* As = smem + p * 16384;
    char* Bs = As + 8192;
    __builtin_amdgcn_global_load_lds(
        (const __attribute__((address_space(1))) unsigned*)(a0p + kb),
        (__attribute__((address_space(3))) unsigned*)(As + wv * 1024), 16, 0, 0);
    __builtin_amdgcn_global_load_lds(
        (const __attribute__((address_space(1))) unsigned*)(a1p + kb),
        (__attribute__((address_space(3))) unsigned*)(As + wv * 1024 + 4096), 16, 0, 0);
    __builtin_amdgcn_global_load_lds(
        (const __attribute__((address_space(1))) unsigned*)(b0p + kb),
        (__attribute__((address_space(3))) unsigned*)(Bs + wv * 1024), 16, 0, 0);
    __builtin_amdgcn_global_load_lds(
        (const __attribute__((address_space(1))) unsigned*)(b1p + kb),
        (__attribute__((address_space(3))) unsigned*)(Bs + wv * 1024 + 4096), 16, 0, 0);
  };

  f32x4 acc[4][4];
#pragma unroll
  for (int i = 0; i < 4; ++i)
#pragma unroll
    for (int j = 0; j < 4; ++j) acc[i][j] = (f32x4){0.f, 0.f, 0.f, 0.f};

  const int KB = K * 2;
  stage_g(0, 0);
  asm volatile("s_waitcnt vmcnt(0)" ::: "memory");
  __syncthreads();
  int p = 0;
  for (int kb = 0; kb < KB; kb += 64) {
    if (kb + 64 < KB) stage_g(p ^ 1, kb + 64);   // prefetch next tile (overlaps compute)
    const char* As = smem + p * 16384;
    const char* Bs = As + 8192;
    bf16x8 fa[4], fb[4];
#pragma unroll
    for (int i = 0; i < 4; ++i) {
      const int r = wm + i * 16 + cc;
      fa[i] = *(const bf16x8*)(As + r * 64 + ((gg ^ ((r >> 1) & 3)) << 4));
    }
#pragma unroll
    for (int j = 0; j < 4; ++j) {
      const int r = wn + j * 16 + cc;
      fb[j] = *(const bf16x8*)(Bs + r * 64 + ((gg ^ ((r >> 1) & 3)) << 4));
    }
    __builtin_amdgcn_s_setprio(1);
#pragma unroll
    for (int i = 0; i < 4; ++i)
#pragma unroll
      for (int j = 0; j < 4; ++j)
        acc[i][j] = __builtin_amdgcn_mfma_f32_16x16x32_bf16(fa[i], fb[j], acc[i][j], 0, 0, 0);
    __builtin_amdgcn_s_setprio(0);
    asm volatile("s_waitcnt vmcnt(0)" ::: "memory");   // next tile's stage landed
    __syncthreads();                                   // all waves done reading buf p
    p ^= 1;
  }

#pragma unroll
  for (int i = 0; i < 4; ++i) {
#pragma unroll
    for (int j = 0; j < 4; ++j) {
      int gm0 = m0 + wm + i * 16 + gg * 4;
      int gn  = n0 + wn + j * 16 + cc;
      float bv = bias[gn];
      if (EPI == 0) {
#pragma unroll
        for (int e = 0; e < 4; ++e)
          outF[(size_t)(gm0 + e) * N + gn] = acc[i][j][e] + bv;
      } else {
        int which = gn / CEMB;
        int r = gn - which * CEMB;
        int hh = r >> 6, dd = r & 63;
        int tt0 = gm0 & (TSEQ - 1), bb = gm0 >> 11;   // 4-aligned: same bb for e=0..3
        if (which == 2) {
          // v -> vT [B,H,D,T]: 4 consecutive tokens contiguous, one 8B store
          ushort* dstv = vd + ((size_t)((bb * NHEAD + hh) * DHEAD + dd)) * TSEQ + tt0;
          uint2 pw;
          pw.x = cvt_pk_bf16(acc[i][j][0] + bv, acc[i][j][1] + bv);
          pw.y = cvt_pk_bf16(acc[i][j][2] + bv, acc[i][j][3] + bv);
          *(uint2*)dstv = pw;
        } else {
          ushort* dst = which == 0 ? qd : kd;
          // q scale: 1/sqrt(D) * log2(e) — softmax computed with exp2
          float sc = (which == 0) ? 0.125f * 1.4426950408889634f : 1.0f;
#pragma unroll
          for (int e = 0; e < 4; ++e)
            dst[(size_t)((bb * NHEAD + hh) * TSEQ + tt0 + e) * DHEAD + dd] =
                f2bf((acc[i][j][e] + bv) * sc);
        }
      }
    }
  }
}

// ---------- flash attention (VGPR-freed, unrolled x2, immediate-offset LDS) ----------
// R16 diagnosis: VALUBusy 63% with VGPR_Count=64 — compiler rematerializes addresses
// chasing 8-wave occupancy that LDS (5 blocks/CU) can't deliver. Fixes:
//  1. __launch_bounds__(256,5): VGPR budget ~102 at the SAME LDS-capped occupancy.
//  2. kt-loop unrolled x2 with LITERAL buffer parity: every ds_read collapses to one
//     of two lane-base VGPRs (lb0/lb1 = cc*128 + ((gg*16)^((cc&7)<<4)) [^64]) plus a
//     compile-time immediate (p*8192 + ct*2048 for K; 16384+(p^1)*8192+dt*2048 for V).
//  3. Common path drops the cross-lane max shuffles: __all() IS the cross-lane check;
//     the shfl reduce runs only in the rare fixup.
// Structure otherwise R16: 1536-block heavy-first grid (slot->XCD), K/V dbuf via
// global_load_lds (rule-21 swizzle), register-P (cvt_pk + permlane chains), eager-exp
// softmax, MFMA l-sum, PV(kt-1) overlapping softmax(kt).
__global__ __launch_bounds__(256, 5)
void attn_fwd(const ushort* __restrict__ qg, const ushort* __restrict__ kg,
              const ushort* __restrict__ vTg, ushort* __restrict__ ybb)
{
  // LDS: K[2] @ 0 (2 x 8KB, swizzled), V[2] @ 16384 (2 x 8KB, swizzled)
  __shared__ __align__(16) char smem[32768];
  const int t = threadIdx.x, lane = t & 63, w = t >> 6;
  const int cc = lane & 15, gg = lane >> 4;
  const int L = blockIdx.x;
  const int slot = L & 7, j = L >> 3;          // j in [0,192)
  const int qt = 31 - j / 6;                   // heavy-first (LPT)
  const int bh = slot + 8 * (j % 6);           // same bh -> same XCD slot
  const int b = bh / NHEAD, h = bh - b * NHEAD;

  const char* Kg = (const char*)(kg + (size_t)bh * TSEQ * DHEAD);   // [T][64], 128B rows
  const char* Vg = (const char*)(vTg + (size_t)bh * TSEQ * DHEAD);  // [64][T], 4096B rows

  const int srow = lane >> 3;                        // row&7 within 8-row chunk
  const int ssw  = ((lane & 7) * 16) ^ (srow << 4);  // pre-swizzled source colbyte

  // shared lane bases for ALL K and V fragment reads (see header comment)
  const int g16s = (gg * 16) ^ ((cc & 7) << 4);
  const char* lb0 = smem + cc * 128 + g16s;
  const char* lb1 = smem + cc * 128 + (g16s ^ 64);

  bf16x8 ones;
#pragma unroll
  for (int i = 0; i < 8; ++i) ones[i] = (short)0x3F80;   // bf16 1.0

  auto stageK = [&](int pb, int kt) {
#pragma unroll
    for (int i = 0; i < 2; ++i) {
      const int c = w * 2 + i;
      const char* gk = Kg + (size_t)(kt * 64 + c * 8 + srow) * 128 + ssw;
      __builtin_amdgcn_global_load_lds(
          (const __attribute__((address_space(1))) unsigned*)gk,
          (__attribute__((address_space(3))) unsigned*)(smem + pb * 8192 + c * 1024),
          16, 0, 0);
    }
  };
  auto stageV = [&](int pb, int kt) {
#pragma unroll
    for (int i = 0; i < 2; ++i) {
      const int c = w * 2 + i;
      const char* gv = Vg + (size_t)(c * 8 + srow) * (TSEQ * 2) + (size_t)kt * 128 + ssw;
      __builtin_amdgcn_global_load_lds(
          (const __attribute__((address_space(1))) unsigned*)gv,
          (__attribute__((address_space(3))) unsigned*)(smem + 16384 + pb * 8192 + c * 1024),
          16, 0, 0);
    }
  };

  const int qrow0 = qt * 64 + w * 16;

  const ushort* Qp = qg + ((size_t)bh * TSEQ + qrow0) * DHEAD;
  bf16x8 fq0 = *(const bf16x8*)(Qp + cc * DHEAD + 8 * gg);
  bf16x8 fq1 = *(const bf16x8*)(Qp + cc * DHEAD + 32 + 8 * gg);

  f32x4 o[4];    // O^T: o[dt][e] = O^T[d = dt*16 + gg*4 + e, q = cc]
  f32x4 l4 = (f32x4){0.f, 0.f, 0.f, 0.f};   // MFMA-ones row-sum acc (elems replicated)
#pragma unroll
  for (int i = 0; i < 4; ++i) o[i] = (f32x4){0.f, 0.f, 0.f, 0.f};
  float m = 0.f;            // running max, log2 domain (eager-exp)
  u32x4 pbf[2];             // P fragments (prev tile), STANDARD B-frag layout
  pbf[0] = (u32x4){0, 0, 0, 0}; pbf[1] = (u32x4){0, 0, 0, 0};

  stageK(0, 0);
  asm volatile("s_waitcnt vmcnt(0)" ::: "memory");
  __syncthreads();

  auto tile = [&](auto PC, int kt) {
    constexpr int P = decltype(PC)::value;
    if (kt < qt) stageK(P ^ 1, kt + 1);   // K for next iter
    stageV(P, kt);                        // V consumed next iter (PV(kt))

    // ---- QK(kt) from K[P] (immediate-offset reads off lb0/lb1) ----
    f32x4 st[4];
#pragma unroll
    for (int ct = 0; ct < 4; ++ct) st[ct] = (f32x4){0.f, 0.f, 0.f, 0.f};
    __builtin_amdgcn_s_setprio(1);
#pragma unroll
    for (int ct = 0; ct < 4; ++ct) {
      bf16x8 fk0 = *(const bf16x8*)(lb0 + P * 8192 + ct * 2048);
      bf16x8 fk1 = *(const bf16x8*)(lb1 + P * 8192 + ct * 2048);
      st[ct] = __builtin_amdgcn_mfma_f32_16x16x32_bf16(fk0, fq0, st[ct], 0, 0, 0);
      st[ct] = __builtin_amdgcn_mfma_f32_16x16x32_bf16(fk1, fq1, st[ct], 0, 0, 0);
    }

    // ---- PV(kt-1) + l-sum(kt-1): P from registers, V[P^1] ----
    if (kt > 0) {
#pragma unroll
      for (int kc = 0; kc < 2; ++kc) {
        bf16x8 pb = __builtin_bit_cast(bf16x8, pbf[kc]);
        l4 = __builtin_amdgcn_mfma_f32_16x16x32_bf16(ones, pb, l4, 0, 0, 0);
        const char* vb = (kc == 0) ? lb0 : lb1;
#pragma unroll
        for (int dt = 0; dt < 4; ++dt) {
          bf16x8 fv = *(const bf16x8*)(vb + 16384 + (P ^ 1) * 8192 + dt * 2048);
          o[dt] = __builtin_amdgcn_mfma_f32_16x16x32_bf16(fv, pb, o[dt], 0, 0, 0);
        }
      }
    }
    __builtin_amdgcn_s_setprio(0);

    // ---- softmax(kt): eager exp with running m ----
    if (kt == qt) {   // causal mask on the diagonal tile
#pragma unroll
      for (int ct = 0; ct < 4; ++ct)
#pragma unroll
        for (int e = 0; e < 4; ++e)
          if (ct * 16 + gg * 4 + e > w * 16 + cc) st[ct][e] = -1e30f;
    }
    f32x4 pe[4];
#pragma unroll
    for (int ct = 0; ct < 4; ++ct)
#pragma unroll
      for (int e = 0; e < 4; ++e) pe[ct][e] = exp2_raw(st[ct][e] - m);
    // per-lane max only; __all() performs the cross-lane reduction for the check
    float ml = fmaxf(fmaxf(st[0][0], st[0][1]), st[0][2]);
    ml = fmaxf(fmaxf(ml, st[0][3]), fmaxf(st[1][0], st[1][1]));
    ml = fmaxf(fmaxf(ml, st[1][2]), fmaxf(st[1][3], st[2][0]));
    ml = fmaxf(fmaxf(ml, st[2][1]), fmaxf(st[2][2], st[2][3]));
    ml = fmaxf(fmaxf(ml, st[3][0]), fmaxf(st[3][1], st[3][2]));
    ml = fmaxf(ml, st[3][3]);
    if (!__all(ml - m <= 11.54f)) {   // rare fixup: shfl-reduce + rescale (no re-exp)
      ml = fmaxf(ml, __shfl_xor(ml, 16, 64));
      ml = fmaxf(ml, __shfl_xor(ml, 32, 64));
      ml = fmaxf(ml, __shfl_xor(ml, 1, 64));   // full-wave max (lanes differ per q-row
      ml = fmaxf(ml, __shfl_xor(ml, 2, 64));   //  -> take wave-wide max; conservative,
      ml = fmaxf(ml, __shfl_xor(ml, 4, 64));   //  keeps m wave-uniform growth rare)
      ml = fmaxf(ml, __shfl_xor(ml, 8, 64));
      float mn = fmaxf(m, ml);
      float al = exp2_raw(m - mn);
#pragma unroll
      for (int dt = 0; dt < 4; ++dt)
#pragma unroll
        for (int e = 0; e < 4; ++e) o[dt][e] *= al;
#pragma unroll
      for (int e = 0; e < 4; ++e) l4[e] *= al;
#pragma unroll
      for (int ct = 0; ct < 4; ++ct)
#pragma unroll
        for (int e = 0; e < 4; ++e) pe[ct][e] *= al;
      m = mn;
    }
    // ---- pack + permlane chains: STANDARD B-frag P(kt) into registers ----
    {
      unsigned X0 = cvt_pk_bf16(pe[0][0], pe[0][1]), X1 = cvt_pk_bf16(pe[0][2], pe[0][3]);
      unsigned Y0 = cvt_pk_bf16(pe[1][0], pe[1][1]), Y1 = cvt_pk_bf16(pe[1][2], pe[1][3]);
      unsigned Z0 = cvt_pk_bf16(pe[2][0], pe[2][1]), Z1 = cvt_pk_bf16(pe[2][2], pe[2][3]);
      unsigned W0 = cvt_pk_bf16(pe[3][0], pe[3][1]), W1 = cvt_pk_bf16(pe[3][2], pe[3][3]);
      permswap32(X0, Y0); permswap16(X0, Y0);
      permswap32(X1, Y1); permswap16(X1, Y1);
      permswap32(Z0, W0); permswap16(Z0, W0);
      permswap32(Z1, W1); permswap16(Z1, W1);
      pbf[0] = (u32x4){X0, X1, Y0, Y1};
      pbf[1] = (u32x4){Z0, Z1, W0, W1};
    }

    asm volatile("s_waitcnt vmcnt(0)" ::: "memory");   // K(kt+1) + V(kt) landed
    __syncthreads();                                   // all waves done with buf P
  };

  for (int kt = 0; kt <= qt; kt += 2) {
    tile(IC<0>{}, kt);
    if (kt + 1 <= qt) tile(IC<1>{}, kt + 1);
  }

  // ---- epilogue: PV(qt) + l-sum(qt) from V[qt&1] ----
  {
    const int pl = qt & 1;
#pragma unroll
    for (int kc = 0; kc < 2; ++kc) {
      bf16x8 pb = __builtin_bit_cast(bf16x8, pbf[kc]);
      l4 = __builtin_amdgcn_mfma_f32_16x16x32_bf16(ones, pb, l4, 0, 0, 0);
      const char* vb = (kc == 0) ? lb0 : lb1;
#pragma unroll
      for (int dt = 0; dt < 4; ++dt) {
        bf16x8 fv = *(const bf16x8*)(vb + 16384 + pl * 8192 + dt * 2048);
        o[dt] = __builtin_amdgcn_mfma_f32_16x16x32_bf16(fv, pb, o[dt], 0, 0, 0);
      }
    }
  }

  float inv = 1.0f / l4[0];
  ushort* yrow = ybb + (size_t)(b * TSEQ + qrow0 + cc) * CEMB + h * DHEAD;
#pragma unroll
  for (int dt = 0; dt < 4; ++dt) {
    uint2 pw;
    pw.x = cvt_pk_bf16(o[dt][0] * inv, o[dt][1] * inv);
    pw.y = cvt_pk_bf16(o[dt][2] * inv, o[dt][3] * inv);
    *(uint2*)(yrow + dt * 16 + gg * 4) = pw;
  }
}

extern "C" void kernel_launch(void* const* d_in, const int* in_sizes, int n_in,
                              void* d_out, int out_size, void* d_ws, size_t ws_size,
                              hipStream_t stream)
{
  (void)in_sizes; (void)n_in; (void)out_size; (void)ws_size;
  const float* x  = (const float*)d_in[0];
  const float* Wa = (const float*)d_in[1];
  const float* ba = (const float*)d_in[2];
  const float* Wo = (const float*)d_in[3];
  const float* bo = (const float*)d_in[4];
  float* out = (float*)d_out;

  char* p = (char*)d_ws;
  ushort* WaT  = (ushort*)p; p += (size_t)3 * CEMB * CEMB * 2;               // [2304][768] bf16
  ushort* WoT  = (ushort*)p; p += (size_t)CEMB * CEMB * 2;                   // [768][768] bf16
  ushort* xb   = (ushort*)p; p += (size_t)NBATCH * TSEQ * CEMB * 2;          // x bf16 [B*T][C]
  ushort* qb   = (ushort*)p; p += (size_t)NBATCH * NHEAD * TSEQ * DHEAD * 2; // [B,H,T,D]
  ushort* kb   = (ushort*)p; p += (size_t)NBATCH * NHEAD * TSEQ * DHEAD * 2;
  ushort* vT   = (ushort*)p; p += (size_t)NBATCH * NHEAD * TSEQ * DHEAD * 2; // [B,H,D,T] (direct)
  ushort* yb   = (ushort*)p; p += (size_t)NBATCH * TSEQ * CEMB * 2;          // attn out bf16

  prep<<<3072 + 96 * 24, 256, 0, stream>>>(x, xb, Wa, WaT, Wo, WoT);
  gemm_bf16<1><<<dim3(3 * CEMB / 128, NBATCH * TSEQ / 128), 256, 0, stream>>>(
      xb, WaT, ba, nullptr, qb, kb, vT, NBATCH * TSEQ, 3 * CEMB, CEMB);
  attn_fwd<<<dim3(1536), 256, 0, stream>>>(qb, kb, vT, yb);
  gemm_bf16<0><<<dim3(CEMB / 128, NBATCH * TSEQ / 128), 256, 0, stream>>>(
      yb, WoT, bo, out, nullptr, nullptr, nullptr, NBATCH * TSEQ, CEMB, CEMB);
}

// Round 18
// 115.041 us; speedup vs baseline: 1.1623x; 1.0333x over previous
//
#include <hip/hip_runtime.h>
#include <hip/hip_bf16.h>

#define NHEAD 12
#define TSEQ 2048
#define CEMB 768
#define DHEAD 64
#define NBATCH 4

typedef __attribute__((ext_vector_type(8))) short bf16x8;
typedef __attribute__((ext_vector_type(4))) float f32x4;
typedef __attribute__((ext_vector_type(4))) unsigned u32x4;

template <int N> struct IC { static constexpr int value = N; };

__device__ __forceinline__ ushort f2bf(float f) {
  union { float f; unsigned u; } v; v.f = f;
  unsigned u = v.u;
  u += 0x7FFFu + ((u >> 16) & 1u);   // RNE to bf16
  return (ushort)(u >> 16);
}

// packed f32x2 -> bf16x2 (1 inst, RNE) — T12 primitive
__device__ __forceinline__ unsigned cvt_pk_bf16(float lo, float hi) {
  unsigned r;
  asm("v_cvt_pk_bf16_f32 %0, %1, %2" : "=v"(r) : "v"(lo), "v"(hi));
  return r;
}

// raw v_exp_f32: D = 2^S0 (scores pre-scaled to log2 domain)
__device__ __forceinline__ float exp2_raw(float x) {
  float r;
  asm("v_exp_f32 %0, %1" : "=v"(r) : "v"(x));
  return r;
}

// v_permlane32_swap_b32 (semantics validated R14):
// new_a = [a.lanes0-31 | b.lanes0-31], new_b = [a.lanes32-63 | b.lanes32-63]
__device__ __forceinline__ void permswap32(unsigned& a, unsigned& b) {
  asm("v_permlane32_swap_b32 %0, %1" : "+v"(a), "+v"(b));
}
// v_permlane16_swap_b32 (validated R15): swap a's odd 16-rows with b's even 16-rows
__device__ __forceinline__ void permswap16(unsigned& a, unsigned& b) {
  asm("v_permlane16_swap_b32 %0, %1" : "+v"(a), "+v"(b));
}

// ---------- fused prep: cast x -> bf16, transpose+cast Wa and Wo ----------
__global__ __launch_bounds__(256)
void prep(const float* __restrict__ x, ushort* __restrict__ xb,
          const float* __restrict__ Wa, ushort* __restrict__ WaT,
          const float* __restrict__ Wo, ushort* __restrict__ WoT)
{
  __shared__ float tile[32][33];
  const int bid = blockIdx.x, t = threadIdx.x;
  if (bid < 3072) {
    int i = (bid * 256 + t) * 8;
    float4 v0 = *(const float4*)(x + i);
    float4 v1 = *(const float4*)(x + i + 4);
    bf16x8 wv;
    wv[0] = (short)f2bf(v0.x); wv[1] = (short)f2bf(v0.y);
    wv[2] = (short)f2bf(v0.z); wv[3] = (short)f2bf(v0.w);
    wv[4] = (short)f2bf(v1.x); wv[5] = (short)f2bf(v1.y);
    wv[6] = (short)f2bf(v1.z); wv[7] = (short)f2bf(v1.w);
    *(bf16x8*)(xb + i) = wv;
    return;
  }
  const int b2 = bid - 3072;
  const int bx = b2 % 96, by = b2 / 96;
  const int tx = t & 31, ty = t >> 5;         // (32,8)
  const float* src; ushort* dst; int C, c0;
  if (bx < 72) { src = Wa; dst = WaT; C = 3 * CEMB; c0 = bx * 32; }
  else         { src = Wo; dst = WoT; C = CEMB;     c0 = (bx - 72) * 32; }
  const int r0 = by * 32;
#pragma unroll
  for (int j = 0; j < 4; ++j)
    tile[ty + j * 8][tx] = src[(size_t)(r0 + ty + j * 8) * C + c0 + tx];
  __syncthreads();
#pragma unroll
  for (int j = 0; j < 4; ++j)
    dst[(size_t)(c0 + ty + j * 8) * CEMB + r0 + tx] = f2bf(tile[tx][ty + j * 8]);
}

// ---------- bf16 MFMA GEMM (depth-2 counted-vmcnt pipeline, XCD-swizzled grid) ----------
// T4: 3 LDS buffers; stage(ik+2) issued per iter; end-of-iter wait = vmcnt(4) (keeps
// the newest stage in flight) + RAW s_barrier (no compiler vmcnt(0) drain) +
// sched_barrier(0) (rule 18). Race-free: each wave's ds_reads complete before its
// MFMAs (compiler lgkm waits), which precede the barrier.
// T1: 1-D grid, xcd = L&7; each XCD owns nM/8 contiguous M-panels (A+B L2-resident).
// EPI=1: q/k scatter to [B,H,T,D] (q pre-scaled by log2e/8); v -> vT [B,H,D,T] direct.
template<int EPI>
__global__ __launch_bounds__(256)
void gemm_bf16(const ushort* __restrict__ A, const ushort* __restrict__ BT,
               const float* __restrict__ bias, float* __restrict__ outF,
               ushort* __restrict__ qd, ushort* __restrict__ kd, ushort* __restrict__ vd,
               int M, int N, int K)
{
  __shared__ __align__(16) char smem[49152];   // 3 bufs x (As 8KB + Bs 8KB)
  const int t = threadIdx.x;
  const int lane = t & 63, wv = t >> 6;
  const int cc = lane & 15, gg = lane >> 4;
  const int nN = N >> 7, nM = M >> 7;
  const int L = blockIdx.x;
  const int xcd = L & 7, li = L >> 3;
  const int mi = li / nN + (nM >> 3) * xcd;    // XCD owns contiguous M-panels
  const int ni = li % nN;
  const int m0 = mi * 128, n0 = ni * 128;
  const int wm = (wv >> 1) * 64, wn = (wv & 1) * 64;

  const int o0 = wv * 1024 + lane * 16;
  const int o1 = o0 + 4096;
  const int r0s = o0 >> 6, s0s = (o0 >> 4) & 3;
  const int r1s = o1 >> 6, s1s = (o1 >> 4) & 3;
  const size_t Kb = (size_t)K * 2;
  const char* a0p = (const char*)A  + (size_t)(m0 + r0s) * Kb + ((s0s ^ ((r0s >> 1) & 3)) << 4);
  const char* a1p = (const char*)A  + (size_t)(m0 + r1s) * Kb + ((s1s ^ ((r1s >> 1) & 3)) << 4);
  const char* b0p = (const char*)BT + (size_t)(n0 + r0s) * Kb + ((s0s ^ ((r0s >> 1) & 3)) << 4);
  const char* b1p = (const char*)BT + (size_t)(n0 + r1s) * Kb + ((s1s ^ ((r1s >> 1) & 3)) << 4);

  auto stage_g = [&](int p, int kb) {
    char* As = smem + p * 16384;
    char* Bs = As + 8192;
    __builtin_amdgcn_global_load_lds(
        (const __attribute__((address_space(1))) unsigned*)(a0p + kb),
        (__attribute__((address_space(3))) unsigned*)(As + wv * 1024), 16, 0, 0);
    __builtin_amdgcn_global_load_lds(
        (const __attribute__((address_space(1))) unsigned*)(a1p + kb),
        (__attribute__((address_space(3))) unsigned*)(As + wv * 1024 + 4096), 16, 0, 0);
    __builtin_amdgcn_global_load_lds(
        (const __attribute__((address_space(1))) unsigned*)(b0p + kb),
        (__attribute__((address_space(3))) unsigned*)(Bs + wv * 1024), 16, 0, 0);
    __builtin_amdgcn_global_load_lds(
        (const __attribute__((address_space(1))) unsigned*)(b1p + kb),
        (__attribute__((address_space(3))) unsigned*)(Bs + wv * 1024 + 4096), 16, 0, 0);
  };

  f32x4 acc[4][4];
#pragma unroll
  for (int i = 0; i < 4; ++i)
#pragma unroll
    for (int j = 0; j < 4; ++j) acc[i][j] = (f32x4){0.f, 0.f, 0.f, 0.f};

  const int NK = (K * 2) / 64;   // 24 for both GEMMs
  stage_g(0, 0);
  stage_g(1, 64);
  asm volatile("s_waitcnt vmcnt(4)" ::: "memory");   // stage 0 landed (1 in flight)
  __builtin_amdgcn_s_barrier();
  __builtin_amdgcn_sched_barrier(0);

  for (int ik = 0; ik < NK; ++ik) {
    const bool pre = (ik + 2 < NK);
    if (pre) stage_g((ik + 2) % 3, (ik + 2) * 64);   // depth-2 prefetch
    const char* As = smem + (ik % 3) * 16384;
    const char* Bs = As + 8192;
    bf16x8 fa[4], fb[4];
#pragma unroll
    for (int i = 0; i < 4; ++i) {
      const int r = wm + i * 16 + cc;
      fa[i] = *(const bf16x8*)(As + r * 64 + ((gg ^ ((r >> 1) & 3)) << 4));
    }
#pragma unroll
    for (int j = 0; j < 4; ++j) {
      const int r = wn + j * 16 + cc;
      fb[j] = *(const bf16x8*)(Bs + r * 64 + ((gg ^ ((r >> 1) & 3)) << 4));
    }
    __builtin_amdgcn_s_setprio(1);
#pragma unroll
    for (int i = 0; i < 4; ++i)
#pragma unroll
      for (int j = 0; j < 4; ++j)
        acc[i][j] = __builtin_amdgcn_mfma_f32_16x16x32_bf16(fa[i], fb[j], acc[i][j], 0, 0, 0);
    __builtin_amdgcn_s_setprio(0);
    if (ik + 1 < NK) {
      if (pre) asm volatile("s_waitcnt vmcnt(4)" ::: "memory");   // stage ik+1 landed
      else     asm volatile("s_waitcnt vmcnt(0)" ::: "memory");   // tail: drain
      __builtin_amdgcn_s_barrier();          // raw barrier: no forced vmcnt(0) drain
      __builtin_amdgcn_sched_barrier(0);
    }
  }

#pragma unroll
  for (int i = 0; i < 4; ++i) {
#pragma unroll
    for (int j = 0; j < 4; ++j) {
      int gm0 = m0 + wm + i * 16 + gg * 4;
      int gn  = n0 + wn + j * 16 + cc;
      float bv = bias[gn];
      if (EPI == 0) {
#pragma unroll
        for (int e = 0; e < 4; ++e)
          outF[(size_t)(gm0 + e) * N + gn] = acc[i][j][e] + bv;
      } else {
        int which = gn / CEMB;
        int r = gn - which * CEMB;
        int hh = r >> 6, dd = r & 63;
        int tt0 = gm0 & (TSEQ - 1), bb = gm0 >> 11;   // 4-aligned: same bb for e=0..3
        if (which == 2) {
          // v -> vT [B,H,D,T]: 4 consecutive tokens contiguous, one 8B store
          ushort* dstv = vd + ((size_t)((bb * NHEAD + hh) * DHEAD + dd)) * TSEQ + tt0;
          uint2 pw;
          pw.x = cvt_pk_bf16(acc[i][j][0] + bv, acc[i][j][1] + bv);
          pw.y = cvt_pk_bf16(acc[i][j][2] + bv, acc[i][j][3] + bv);
          *(uint2*)dstv = pw;
        } else {
          ushort* dst = which == 0 ? qd : kd;
          // q scale: 1/sqrt(D) * log2(e) — softmax computed with exp2
          float sc = (which == 0) ? 0.125f * 1.4426950408889634f : 1.0f;
#pragma unroll
          for (int e = 0; e < 4; ++e)
            dst[(size_t)((bb * NHEAD + hh) * TSEQ + tt0 + e) * DHEAD + dd] =
                f2bf((acc[i][j][e] + bv) * sc);
        }
      }
    }
  }
}

// ---------- flash attention (R17-proven: VGPR-freed, unrolled x2, immediate-offset LDS)
__global__ __launch_bounds__(256, 5)
void attn_fwd(const ushort* __restrict__ qg, const ushort* __restrict__ kg,
              const ushort* __restrict__ vTg, ushort* __restrict__ ybb)
{
  // LDS: K[2] @ 0 (2 x 8KB, swizzled), V[2] @ 16384 (2 x 8KB, swizzled)
  __shared__ __align__(16) char smem[32768];
  const int t = threadIdx.x, lane = t & 63, w = t >> 6;
  const int cc = lane & 15, gg = lane >> 4;
  const int L = blockIdx.x;
  const int slot = L & 7, j = L >> 3;          // j in [0,192)
  const int qt = 31 - j / 6;                   // heavy-first (LPT)
  const int bh = slot + 8 * (j % 6);           // same bh -> same XCD slot
  const int b = bh / NHEAD, h = bh - b * NHEAD;

  const char* Kg = (const char*)(kg + (size_t)bh * TSEQ * DHEAD);   // [T][64], 128B rows
  const char* Vg = (const char*)(vTg + (size_t)bh * TSEQ * DHEAD);  // [64][T], 4096B rows

  const int srow = lane >> 3;                        // row&7 within 8-row chunk
  const int ssw  = ((lane & 7) * 16) ^ (srow << 4);  // pre-swizzled source colbyte

  // shared lane bases for ALL K and V fragment reads
  const int g16s = (gg * 16) ^ ((cc & 7) << 4);
  const char* lb0 = smem + cc * 128 + g16s;
  const char* lb1 = smem + cc * 128 + (g16s ^ 64);

  bf16x8 ones;
#pragma unroll
  for (int i = 0; i < 8; ++i) ones[i] = (short)0x3F80;   // bf16 1.0

  auto stageK = [&](int pb, int kt) {
#pragma unroll
    for (int i = 0; i < 2; ++i) {
      const int c = w * 2 + i;
      const char* gk = Kg + (size_t)(kt * 64 + c * 8 + srow) * 128 + ssw;
      __builtin_amdgcn_global_load_lds(
          (const __attribute__((address_space(1))) unsigned*)gk,
          (__attribute__((address_space(3))) unsigned*)(smem + pb * 8192 + c * 1024),
          16, 0, 0);
    }
  };
  auto stageV = [&](int pb, int kt) {
#pragma unroll
    for (int i = 0; i < 2; ++i) {
      const int c = w * 2 + i;
      const char* gv = Vg + (size_t)(c * 8 + srow) * (TSEQ * 2) + (size_t)kt * 128 + ssw;
      __builtin_amdgcn_global_load_lds(
          (const __attribute__((address_space(1))) unsigned*)gv,
          (__attribute__((address_space(3))) unsigned*)(smem + 16384 + pb * 8192 + c * 1024),
          16, 0, 0);
    }
  };

  const int qrow0 = qt * 64 + w * 16;

  const ushort* Qp = qg + ((size_t)bh * TSEQ + qrow0) * DHEAD;
  bf16x8 fq0 = *(const bf16x8*)(Qp + cc * DHEAD + 8 * gg);
  bf16x8 fq1 = *(const bf16x8*)(Qp + cc * DHEAD + 32 + 8 * gg);

  f32x4 o[4];    // O^T: o[dt][e] = O^T[d = dt*16 + gg*4 + e, q = cc]
  f32x4 l4 = (f32x4){0.f, 0.f, 0.f, 0.f};   // MFMA-ones row-sum acc (elems replicated)
#pragma unroll
  for (int i = 0; i < 4; ++i) o[i] = (f32x4){0.f, 0.f, 0.f, 0.f};
  float m = 0.f;            // running max, log2 domain (eager-exp)
  u32x4 pbf[2];             // P fragments (prev tile), STANDARD B-frag layout
  pbf[0] = (u32x4){0, 0, 0, 0}; pbf[1] = (u32x4){0, 0, 0, 0};

  stageK(0, 0);
  asm volatile("s_waitcnt vmcnt(0)" ::: "memory");
  __syncthreads();

  auto tile = [&](auto PC, int kt) {
    constexpr int P = decltype(PC)::value;
    if (kt < qt) stageK(P ^ 1, kt + 1);   // K for next iter
    stageV(P, kt);                        // V consumed next iter (PV(kt))

    // ---- QK(kt) from K[P] (immediate-offset reads off lb0/lb1) ----
    f32x4 st[4];
#pragma unroll
    for (int ct = 0; ct < 4; ++ct) st[ct] = (f32x4){0.f, 0.f, 0.f, 0.f};
    __builtin_amdgcn_s_setprio(1);
#pragma unroll
    for (int ct = 0; ct < 4; ++ct) {
      bf16x8 fk0 = *(const bf16x8*)(lb0 + P * 8192 + ct * 2048);
      bf16x8 fk1 = *(const bf16x8*)(lb1 + P * 8192 + ct * 2048);
      st[ct] = __builtin_amdgcn_mfma_f32_16x16x32_bf16(fk0, fq0, st[ct], 0, 0, 0);
      st[ct] = __builtin_amdgcn_mfma_f32_16x16x32_bf16(fk1, fq1, st[ct], 0, 0, 0);
    }

    // ---- PV(kt-1) + l-sum(kt-1): P from registers, V[P^1] ----
    if (kt > 0) {
#pragma unroll
      for (int kc = 0; kc < 2; ++kc) {
        bf16x8 pb = __builtin_bit_cast(bf16x8, pbf[kc]);
        l4 = __builtin_amdgcn_mfma_f32_16x16x32_bf16(ones, pb, l4, 0, 0, 0);
        const char* vb = (kc == 0) ? lb0 : lb1;
#pragma unroll
        for (int dt = 0; dt < 4; ++dt) {
          bf16x8 fv = *(const bf16x8*)(vb + 16384 + (P ^ 1) * 8192 + dt * 2048);
          o[dt] = __builtin_amdgcn_mfma_f32_16x16x32_bf16(fv, pb, o[dt], 0, 0, 0);
        }
      }
    }
    __builtin_amdgcn_s_setprio(0);

    // ---- softmax(kt): eager exp with running m ----
    if (kt == qt) {   // causal mask on the diagonal tile
#pragma unroll
      for (int ct = 0; ct < 4; ++ct)
#pragma unroll
        for (int e = 0; e < 4; ++e)
          if (ct * 16 + gg * 4 + e > w * 16 + cc) st[ct][e] = -1e30f;
    }
    f32x4 pe[4];
#pragma unroll
    for (int ct = 0; ct < 4; ++ct)
#pragma unroll
      for (int e = 0; e < 4; ++e) pe[ct][e] = exp2_raw(st[ct][e] - m);
    // per-lane max only; __all() performs the cross-lane reduction for the check
    float ml = fmaxf(fmaxf(st[0][0], st[0][1]), st[0][2]);
    ml = fmaxf(fmaxf(ml, st[0][3]), fmaxf(st[1][0], st[1][1]));
    ml = fmaxf(fmaxf(ml, st[1][2]), fmaxf(st[1][3], st[2][0]));
    ml = fmaxf(fmaxf(ml, st[2][1]), fmaxf(st[2][2], st[2][3]));
    ml = fmaxf(fmaxf(ml, st[3][0]), fmaxf(st[3][1], st[3][2]));
    ml = fmaxf(ml, st[3][3]);
    if (!__all(ml - m <= 11.54f)) {   // rare fixup: shfl-reduce + rescale (no re-exp)
      ml = fmaxf(ml, __shfl_xor(ml, 16, 64));
      ml = fmaxf(ml, __shfl_xor(ml, 32, 64));
      ml = fmaxf(ml, __shfl_xor(ml, 1, 64));
      ml = fmaxf(ml, __shfl_xor(ml, 2, 64));
      ml = fmaxf(ml, __shfl_xor(ml, 4, 64));
      ml = fmaxf(ml, __shfl_xor(ml, 8, 64));
      float mn = fmaxf(m, ml);
      float al = exp2_raw(m - mn);
#pragma unroll
      for (int dt = 0; dt < 4; ++dt)
#pragma unroll
        for (int e = 0; e < 4; ++e) o[dt][e] *= al;
#pragma unroll
      for (int e = 0; e < 4; ++e) l4[e] *= al;
#pragma unroll
      for (int ct = 0; ct < 4; ++ct)
#pragma unroll
        for (int e = 0; e < 4; ++e) pe[ct][e] *= al;
      m = mn;
    }
    // ---- pack + permlane chains: STANDARD B-frag P(kt) into registers ----
    {
      unsigned X0 = cvt_pk_bf16(pe[0][0], pe[0][1]), X1 = cvt_pk_bf16(pe[0][2], pe[0][3]);
      unsigned Y0 = cvt_pk_bf16(pe[1][0], pe[1][1]), Y1 = cvt_pk_bf16(pe[1][2], pe[1][3]);
      unsigned Z0 = cvt_pk_bf16(pe[2][0], pe[2][1]), Z1 = cvt_pk_bf16(pe[2][2], pe[2][3]);
      unsigned W0 = cvt_pk_bf16(pe[3][0], pe[3][1]), W1 = cvt_pk_bf16(pe[3][2], pe[3][3]);
      permswap32(X0, Y0); permswap16(X0, Y0);
      permswap32(X1, Y1); permswap16(X1, Y1);
      permswap32(Z0, W0); permswap16(Z0, W0);
      permswap32(Z1, W1); permswap16(Z1, W1);
      pbf[0] = (u32x4){X0, X1, Y0, Y1};
      pbf[1] = (u32x4){Z0, Z1, W0, W1};
    }

    asm volatile("s_waitcnt vmcnt(0)" ::: "memory");   // K(kt+1) + V(kt) landed
    __syncthreads();                                   // all waves done with buf P
  };

  for (int kt = 0; kt <= qt; kt += 2) {
    tile(IC<0>{}, kt);
    if (kt + 1 <= qt) tile(IC<1>{}, kt + 1);
  }

  // ---- epilogue: PV(qt) + l-sum(qt) from V[qt&1] ----
  {
    const int pl = qt & 1;
#pragma unroll
    for (int kc = 0; kc < 2; ++kc) {
      bf16x8 pb = __builtin_bit_cast(bf16x8, pbf[kc]);
      l4 = __builtin_amdgcn_mfma_f32_16x16x32_bf16(ones, pb, l4, 0, 0, 0);
      const char* vb = (kc == 0) ? lb0 : lb1;
#pragma unroll
      for (int dt = 0; dt < 4; ++dt) {
        bf16x8 fv = *(const bf16x8*)(vb + 16384 + pl * 8192 + dt * 2048);
        o[dt] = __builtin_amdgcn_mfma_f32_16x16x32_bf16(fv, pb, o[dt], 0, 0, 0);
      }
    }
  }

  float inv = 1.0f / l4[0];
  ushort* yrow = ybb + (size_t)(b * TSEQ + qrow0 + cc) * CEMB + h * DHEAD;
#pragma unroll
  for (int dt = 0; dt < 4; ++dt) {
    uint2 pw;
    pw.x = cvt_pk_bf16(o[dt][0] * inv, o[dt][1] * inv);
    pw.y = cvt_pk_bf16(o[dt][2] * inv, o[dt][3] * inv);
    *(uint2*)(yrow + dt * 16 + gg * 4) = pw;
  }
}

extern "C" void kernel_launch(void* const* d_in, const int* in_sizes, int n_in,
                              void* d_out, int out_size, void* d_ws, size_t ws_size,
                              hipStream_t stream)
{
  (void)in_sizes; (void)n_in; (void)out_size; (void)ws_size;
  const float* x  = (const float*)d_in[0];
  const float* Wa = (const float*)d_in[1];
  const float* ba = (const float*)d_in[2];
  const float* Wo = (const float*)d_in[3];
  const float* bo = (const float*)d_in[4];
  float* out = (float*)d_out;

  char* p = (char*)d_ws;
  ushort* WaT  = (ushort*)p; p += (size_t)3 * CEMB * CEMB * 2;               // [2304][768] bf16
  ushort* WoT  = (ushort*)p; p += (size_t)CEMB * CEMB * 2;                   // [768][768] bf16
  ushort* xb   = (ushort*)p; p += (size_t)NBATCH * TSEQ * CEMB * 2;          // x bf16 [B*T][C]
  ushort* qb   = (ushort*)p; p += (size_t)NBATCH * NHEAD * TSEQ * DHEAD * 2; // [B,H,T,D]
  ushort* kb   = (ushort*)p; p += (size_t)NBATCH * NHEAD * TSEQ * DHEAD * 2;
  ushort* vT   = (ushort*)p; p += (size_t)NBATCH * NHEAD * TSEQ * DHEAD * 2; // [B,H,D,T] (direct)
  ushort* yb   = (ushort*)p; p += (size_t)NBATCH * TSEQ * CEMB * 2;          // attn out bf16

  prep<<<3072 + 96 * 24, 256, 0, stream>>>(x, xb, Wa, WaT, Wo, WoT);
  gemm_bf16<1><<<dim3((NBATCH * TSEQ / 128) * (3 * CEMB / 128)), 256, 0, stream>>>(
      xb, WaT, ba, nullptr, qb, kb, vT, NBATCH * TSEQ, 3 * CEMB, CEMB);
  attn_fwd<<<dim3(1536), 256, 0, stream>>>(qb, kb, vT, yb);
  gemm_bf16<0><<<dim3((NBATCH * TSEQ / 128) * (CEMB / 128)), 256, 0, stream>>>(
      yb, WoT, bo, out, nullptr, nullptr, nullptr, NBATCH * TSEQ, CEMB, CEMB);
}